// Round 4
// baseline (145.783 us; speedup 1.0000x reference)
//
#include <hip/hip_runtime.h>
#include <hip/hip_bf16.h>
#include <stdint.h>
#include <stddef.h>

using bf16 = __hip_bfloat16;
using bf16x8 = __attribute__((ext_vector_type(8))) short;   // 8 bf16 in 4 VGPRs
using f32x4  = __attribute__((ext_vector_type(4))) float;
using f32x16 = __attribute__((ext_vector_type(16))) float;
typedef unsigned int u32x2 __attribute__((ext_vector_type(2)));
typedef unsigned int u32x4 __attribute__((ext_vector_type(4)));

#define MFMA16(a, b, c) __builtin_amdgcn_mfma_f32_16x16x32_bf16((a), (b), (c), 0, 0, 0)
#define MFMA32(a, b, c) __builtin_amdgcn_mfma_f32_32x32x16_bf16((a), (b), (c), 0, 0, 0)

#define GLD16(g, l)                                                            \
  __builtin_amdgcn_global_load_lds(                                            \
      (const __attribute__((address_space(1))) void*)(g),                      \
      (__attribute__((address_space(3))) void*)(l), 16, 0, 0)

__device__ __forceinline__ float exp2_fast(float x) {
#if __has_builtin(__builtin_amdgcn_exp2f)
  return __builtin_amdgcn_exp2f(x);
#else
  return __expf(x * 0.69314718056f);
#endif
}

__device__ __forceinline__ float fmax3(float a, float b, float c) {
  return fmaxf(fmaxf(a, b), c);   // fuses to v_max3_f32
}

__device__ __forceinline__ unsigned int cvtpk_bf16(float lo, float hi) {
  unsigned int r;
  asm("v_cvt_pk_bf16_f32 %0, %1, %2" : "=v"(r) : "v"(lo), "v"(hi));
  return r;
}

__device__ __forceinline__ void permswap(unsigned int& a, unsigned int& b, int hi) {
#if __has_builtin(__builtin_amdgcn_permlane32_swap)
  u32x2 r = __builtin_amdgcn_permlane32_swap(a, b, false, false);
  a = r.x;
  b = r.y;
#else
  unsigned int sa = __shfl_xor((unsigned int)a, 32, 64);
  unsigned int sb = __shfl_xor((unsigned int)b, 32, 64);
  unsigned int an = hi ? sb : a;
  unsigned int bn = hi ? b : sa;
  a = an; b = bn;
#endif
}

// ---------------------------------------------------------------- conversions

__global__ void convert_x(const float* __restrict__ x, bf16* __restrict__ out) {
  const int i = blockIdx.x * 256 + threadIdx.x;
  const float4 v = ((const float4*)x)[i];
  __hip_bfloat162* o2 = (__hip_bfloat162*)(out + (size_t)i * 4);
  o2[0] = __float22bfloat162_rn(make_float2(v.x, v.y));
  o2[1] = __float22bfloat162_rn(make_float2(v.z, v.w));
}

__global__ void convert_w(const float* __restrict__ W0, const float* __restrict__ W1,
                          const float* __restrict__ W2, const float* __restrict__ W3,
                          bf16* __restrict__ Wt) {
  __shared__ float t[32][33];
  const int bx = blockIdx.x;
  const int mat = bx >> 10;
  const float* W = (mat == 0) ? W0 : (mat == 1) ? W1 : (mat == 2) ? W2 : W3;
  const int rem = bx & 1023;
  const int k0 = (rem >> 5) * 32, n0 = (rem & 31) * 32;
  const int c = threadIdx.x & 31, r0 = (threadIdx.x >> 5) * 4;
#pragma unroll
  for (int i = 0; i < 4; ++i) {
    const int r = r0 + i;
    t[r][c] = W[(size_t)(k0 + r) * 1024 + n0 + c];
  }
  __syncthreads();
  bf16* dst = Wt + (size_t)mat * 1024 * 1024;
#pragma unroll
  for (int i = 0; i < 4; ++i) {
    const int rn = r0 + i;
    dst[(size_t)(n0 + rn) * 1024 + k0 + c] = __float2bfloat16(t[c][rn]);
  }
}

__global__ void concat_bias(const float* __restrict__ bq, const float* __restrict__ bk,
                            const float* __restrict__ bv, const float* __restrict__ bo,
                            float* __restrict__ dst) {
  const int i = blockIdx.x * 256 + threadIdx.x;
  const float* src = (i < 1024) ? bq : (i < 2048) ? bk : (i < 3072) ? bv : bo;
  dst[i] = src[i & 1023];
}

// ---------------------------------------------------------------- GEMM (A[M,K] * Bt[N,K]^T + bias)

template <int MODE>
__global__ __launch_bounds__(256)
void gemm_bt(const bf16* __restrict__ A, const bf16* __restrict__ Bt,
             const float* __restrict__ bias,
             bf16* __restrict__ Qb, bf16* __restrict__ Kb, bf16* __restrict__ Vt,
             float* __restrict__ Of, int K) {
  __shared__ bf16 As[128 * 32];
  __shared__ bf16 Bs[128 * 32];
  const int tid = threadIdx.x;
  const int lane = tid & 63, w = tid >> 6;
  const int wr = w >> 1, wc = w & 1;
  const int lrow = lane & 15, lgk = lane >> 4;
  const int bm = blockIdx.y * 128, bn = blockIdx.x * 128;
  f32x4 acc[4][4] = {};
  const bf16* Ab = A + (size_t)bm * K;
  const bf16* Bb = Bt + (size_t)bn * K;
  const int e0 = tid, e1 = 256 + tid;

  for (int k0 = 0; k0 < K; k0 += 32) {
    GLD16(Ab + (size_t)(e0 >> 2) * K + k0 + (e0 & 3) * 8, As + e0 * 8);
    GLD16(Ab + (size_t)(e1 >> 2) * K + k0 + (e1 & 3) * 8, As + e1 * 8);
    GLD16(Bb + (size_t)(e0 >> 2) * K + k0 + (e0 & 3) * 8, Bs + e0 * 8);
    GLD16(Bb + (size_t)(e1 >> 2) * K + k0 + (e1 & 3) * 8, Bs + e1 * 8);
    asm volatile("s_waitcnt vmcnt(0)" ::: "memory");
    __syncthreads();
    bf16x8 af[4], bfr[4];
#pragma unroll
    for (int m = 0; m < 4; ++m)
      af[m] = *(const bf16x8*)(As + (wr * 64 + m * 16 + lrow) * 32 + lgk * 8);
#pragma unroll
    for (int n = 0; n < 4; ++n)
      bfr[n] = *(const bf16x8*)(Bs + (wc * 64 + n * 16 + lrow) * 32 + lgk * 8);
#pragma unroll
    for (int m = 0; m < 4; ++m)
#pragma unroll
      for (int n = 0; n < 4; ++n)
        acc[m][n] = MFMA16(af[m], bfr[n], acc[m][n]);
    __syncthreads();
  }

  if constexpr (MODE == 0) {
    if (bn >= 2048) {
      // -------- V path: LDS transpose -> coalesced Vt[bh, d, t] writes
      __shared__ bf16 vstage[64][130];   // +2 pad: bank-conflict-free col reads
      const int b = bm >> 11;
      const int t0 = bm & 2047;
      const int h0 = (bn - 2048) >> 6;
#pragma unroll
      for (int h2 = 0; h2 < 2; ++h2) {
        if (wr == h2) {
#pragma unroll
          for (int m = 0; m < 4; ++m)
#pragma unroll
            for (int n = 0; n < 4; ++n) {
              const int cl = wc * 64 + n * 16 + lrow;
              const float bv_ = bias[bn + cl];
#pragma unroll
              for (int j = 0; j < 4; ++j)
                vstage[m * 16 + lgk * 4 + j][cl] =
                    __float2bfloat16(acc[m][n][j] + bv_);
            }
        }
        __syncthreads();
#pragma unroll
        for (int it = 0; it < 32; ++it) {
          const int c = it * 4 + w;
          const int hh = h0 + (c >> 6), d = c & 63;
          Vt[((size_t)(b * 16 + hh) * 64 + d) * 2048 + t0 + h2 * 64 + lane] =
              vstage[lane][c];
        }
        __syncthreads();
      }
    } else {
      // -------- Q/K path
#pragma unroll
      for (int m = 0; m < 4; ++m) {
#pragma unroll
        for (int n = 0; n < 4; ++n) {
          const int col = bn + wc * 64 + n * 16 + lrow;
          const float bv_ = bias[col];
          const int row0 = bm + wr * 64 + m * 16 + lgk * 4;
          const int which = col >> 10;
          const int hd = col & 1023;
          const int h = hd >> 6, d = hd & 63;
#pragma unroll
          for (int j = 0; j < 4; ++j) {
            const int row = row0 + j;
            const int b = row >> 11, t = row & 2047;
            const int bh = b * 16 + h;
            const float v = acc[m][n][j] + bv_;
            if (which == 0)
              Qb[((size_t)bh * 2048 + t) * 64 + d] =
                  __float2bfloat16(v * 0.18033688f);   // fold 1/sqrt(64)*log2(e)
            else
              Kb[((size_t)bh * 2048 + t) * 64 + d] = __float2bfloat16(v);
          }
        }
      }
    }
  } else {
#pragma unroll
    for (int m = 0; m < 4; ++m) {
#pragma unroll
      for (int n = 0; n < 4; ++n) {
        const int col = bn + wc * 64 + n * 16 + lrow;
        const float bv_ = bias[col];
        const int row0 = bm + wr * 64 + m * 16 + lgk * 4;
#pragma unroll
        for (int j = 0; j < 4; ++j)
          Of[(size_t)(row0 + j) * 1024 + col] = acc[m][n][j] + bv_;
      }
    }
  }
}

// ---------------------------------------------------------------- flash attention
// Swapped QK^T, in-register softmax, LDS-staged K/V (double-buffered, counted
// vmcnt, XOR-swizzle), software-pipelined: SM(t-1)/PV(t-1) overlap QK^T(t).
__global__ __launch_bounds__(256, 2)
void attn_kernel(const bf16* __restrict__ Q, const bf16* __restrict__ Kb,
                 const bf16* __restrict__ Vt, bf16* __restrict__ ctx) {
  __shared__ bf16 Kl[2][64 * 64];
  __shared__ bf16 Vl[2][64 * 64];

  const int tid = threadIdx.x, lane = tid & 63, w = tid >> 6;
  const int lo5 = lane & 31, hi = lane >> 5;

  const int bid = blockIdx.x;
  const int xcd = bid & 7, idx = bid >> 3;
  const int bh = (xcd << 2) | (idx >> 4);
  const int qt = idx & 15;
  const int q0 = qt * 128 + w * 32;

  const bf16* Qbh = Q + (size_t)bh * 2048 * 64;
  const bf16* Kbh = Kb + (size_t)bh * 2048 * 64;
  const bf16* Vbh = Vt + (size_t)bh * 64 * 2048;

  bf16x8 qf[4];
#pragma unroll
  for (int f = 0; f < 4; ++f)
    qf[f] = *(const bf16x8*)(Qbh + (size_t)(q0 + lo5) * 64 + f * 16 + hi * 8);

  f32x16 o0 = {}, o1 = {};
  float m2 = -1e30f;
  float lsum = 0.f;

  auto stage = [&](int buf, int kv) {
#pragma unroll
    for (int i = 0; i < 2; ++i) {
      const int c = (w * 2 + i) * 64 + lane;
      const int r = c >> 3, j = c & 7;
      const int js = (j ^ (r & 7)) * 8;
      GLD16(Kbh + (size_t)(kv + r) * 64 + js, &Kl[buf][c * 8]);
      GLD16(Vbh + (size_t)r * 2048 + kv + js, &Vl[buf][c * 8]);
    }
  };

  bf16x8 pa[4];

  // softmax on raw scores (in-place exp), update m2/lsum, rescale o, build pa
  auto softmax_pa = [&](f32x16& s0, f32x16& s1) {
    float r1[11];
#pragma unroll
    for (int i = 0; i < 5; ++i)
      r1[i] = fmax3(s0[3 * i], s0[3 * i + 1], s0[3 * i + 2]);
    r1[5] = fmax3(s0[15], s1[0], s1[1]);
#pragma unroll
    for (int i = 0; i < 4; ++i)
      r1[6 + i] = fmax3(s1[2 + 3 * i], s1[3 + 3 * i], s1[4 + 3 * i]);
    r1[10] = fmaxf(s1[14], s1[15]);
    float r2[4];
#pragma unroll
    for (int i = 0; i < 3; ++i) r2[i] = fmax3(r1[3 * i], r1[3 * i + 1], r1[3 * i + 2]);
    r2[3] = fmaxf(r1[9], r1[10]);
    const float pm = fmaxf(fmax3(r2[0], r2[1], r2[2]), r2[3]);
    if (!__all(pm <= m2 + 11.5416f)) {   // defer-max (THR=8 nats, log2 domain)
      const float mx = fmaxf(pm, __shfl_xor(pm, 32, 64));
      const float mn = fmaxf(m2, mx);
      const float corr = exp2_fast(m2 - mn);
      m2 = mn;
      lsum *= corr;
#pragma unroll
      for (int j = 0; j < 16; ++j) { o0[j] *= corr; o1[j] *= corr; }
    }
#pragma unroll
    for (int j = 0; j < 16; ++j) s0[j] = exp2_fast(s0[j] - m2);
#pragma unroll
    for (int j = 0; j < 16; ++j) s1[j] = exp2_fast(s1[j] - m2);
    float a8[8];
#pragma unroll
    for (int j = 0; j < 8; ++j) a8[j] = (s0[j] + s0[j + 8]) + (s1[j] + s1[j + 8]);
    float a4[4];
#pragma unroll
    for (int j = 0; j < 4; ++j) a4[j] = a8[j] + a8[j + 4];
    lsum += (a4[0] + a4[1]) + (a4[2] + a4[3]);
    // pa[ks]: ks=0,1 from s0, ks=2,3 from s1
#pragma unroll
    for (int ks = 0; ks < 4; ++ks) {
      const f32x16& s = (ks < 2) ? s0 : s1;
      const int b0 = (ks & 1) * 8;
      unsigned int a0 = cvtpk_bf16(s[b0 + 0], s[b0 + 1]);
      unsigned int c0 = cvtpk_bf16(s[b0 + 4], s[b0 + 5]);
      unsigned int a1 = cvtpk_bf16(s[b0 + 2], s[b0 + 3]);
      unsigned int c1 = cvtpk_bf16(s[b0 + 6], s[b0 + 7]);
      permswap(a0, c0, hi);
      permswap(a1, c1, hi);
      u32x4 tt;
      tt.x = a0; tt.y = a1; tt.z = c0; tt.w = c1;
      pa[ks] = __builtin_bit_cast(bf16x8, tt);
    }
  };

  f32x16 sA0, sA1, sB0, sB1;
  bf16x8 vfA[8], vfB[8];

  // one pipeline step: QK^T(t) into sC/vfC; SM+PV of (t-1) from sP/vfP
  auto step = [&](int t, f32x16& sC0, f32x16& sC1, bf16x8 (&vfC)[8],
                  f32x16& sP0, f32x16& sP1, bf16x8 (&vfP)[8]) {
    const int cur = t & 1;
    const int kv = t << 6;
    if (t < 31) stage(cur ^ 1, kv + 64);
    if (t < 31)
      asm volatile("s_waitcnt vmcnt(4)" ::: "memory");
    else
      asm volatile("s_waitcnt vmcnt(0)" ::: "memory");
    __builtin_amdgcn_s_barrier();            // B1: tile t visible
    bf16x8 kf[8];
#pragma unroll
    for (int kt = 0; kt < 2; ++kt)
#pragma unroll
      for (int f = 0; f < 4; ++f) {
        const int r = kt * 32 + lo5;
        kf[kt * 4 + f] =
            *(const bf16x8*)(&Kl[cur][(r * 8 + (((f << 1) + hi) ^ (r & 7))) * 8]);
      }
#pragma unroll
    for (int dt = 0; dt < 2; ++dt)
#pragma unroll
      for (int ks = 0; ks < 4; ++ks) {
        const int r = dt * 32 + lo5;
        vfC[dt * 4 + ks] =
            *(const bf16x8*)(&Vl[cur][(r * 8 + (((ks << 1) + hi) ^ (r & 7))) * 8]);
      }
    if (t > 0) softmax_pa(sP0, sP1);         // VALU, overlaps ds_read latency
    asm volatile("s_waitcnt lgkmcnt(0)" ::: "memory");
    __builtin_amdgcn_sched_barrier(0);
    __builtin_amdgcn_s_barrier();            // B2: reads of buf[cur] done
    __builtin_amdgcn_s_setprio(1);
    sC0 = f32x16{};
    sC1 = f32x16{};
#pragma unroll
    for (int f = 0; f < 4; ++f) sC0 = MFMA32(kf[f], qf[f], sC0);
#pragma unroll
    for (int f = 0; f < 4; ++f) sC1 = MFMA32(kf[4 + f], qf[f], sC1);
    if (t > 0) {
#pragma unroll
      for (int ks = 0; ks < 4; ++ks) {
        o0 = MFMA32(vfP[ks], pa[ks], o0);
        o1 = MFMA32(vfP[4 + ks], pa[ks], o1);
      }
    }
    __builtin_amdgcn_s_setprio(0);
  };

  stage(0, 0);

  step(0, sA0, sA1, vfA, sB0, sB1, vfB);
  for (int tt = 1; tt < 31; tt += 2) {
    step(tt, sB0, sB1, vfB, sA0, sA1, vfA);
    step(tt + 1, sA0, sA1, vfA, sB0, sB1, vfB);
  }
  step(31, sB0, sB1, vfB, sA0, sA1, vfA);

  // epilogue: SM(31) + PV(31)
  softmax_pa(sB0, sB1);
#pragma unroll
  for (int ks = 0; ks < 4; ++ks) {
    o0 = MFMA32(vfB[ks], pa[ks], o0);
    o1 = MFMA32(vfB[4 + ks], pa[ks], o1);
  }

  lsum += __shfl_xor(lsum, 32, 64);
  const float inv = 1.f / lsum;
  const int b = bh >> 4, h = bh & 15;
  bf16* crow = ctx + (size_t)(b * 2048 + q0 + lo5) * 1024 + h * 64;
#pragma unroll
  for (int g = 0; g < 4; ++g) {
    uint2 pk0, pk1;
    pk0.x = cvtpk_bf16(o0[4 * g + 0] * inv, o0[4 * g + 1] * inv);
    pk0.y = cvtpk_bf16(o0[4 * g + 2] * inv, o0[4 * g + 3] * inv);
    pk1.x = cvtpk_bf16(o1[4 * g + 0] * inv, o1[4 * g + 1] * inv);
    pk1.y = cvtpk_bf16(o1[4 * g + 2] * inv, o1[4 * g + 3] * inv);
    *(uint2*)(crow + 8 * g + 4 * hi) = pk0;
    *(uint2*)(crow + 32 + 8 * g + 4 * hi) = pk1;
  }
}

// ---------------------------------------------------------------- launch

extern "C" void kernel_launch(void* const* d_in, const int* in_sizes, int n_in,
                              void* d_out, int out_size, void* d_ws, size_t ws_size,
                              hipStream_t stream) {
  const float* x  = (const float*)d_in[0];
  const float* Wq = (const float*)d_in[1];
  const float* bq = (const float*)d_in[2];
  const float* Wk = (const float*)d_in[3];
  const float* bk = (const float*)d_in[4];
  const float* Wv = (const float*)d_in[5];
  const float* bv = (const float*)d_in[6];
  const float* Wo = (const float*)d_in[7];
  const float* bo = (const float*)d_in[8];
  float* out = (float*)d_out;

  char* ws = (char*)d_ws;
  bf16* xb  = (bf16*)(ws);
  bf16* Wt  = (bf16*)(ws + ((size_t)8 << 20));
  bf16* Qb  = (bf16*)(ws + ((size_t)16 << 20));
  bf16* Kb  = (bf16*)(ws + ((size_t)24 << 20));
  bf16* Vt  = (bf16*)(ws + ((size_t)32 << 20));
  bf16* ctx = (bf16*)(ws + ((size_t)40 << 20));
  float* ba = (float*)(ws + ((size_t)48 << 20));

  convert_x<<<dim3(4096), dim3(256), 0, stream>>>(x, xb);
  convert_w<<<dim3(4096), dim3(256), 0, stream>>>(Wq, Wk, Wv, Wo, Wt);
  concat_bias<<<dim3(16), dim3(256), 0, stream>>>(bq, bk, bv, bo, ba);

  gemm_bt<0><<<dim3(24, 32), dim3(256), 0, stream>>>(xb, Wt, ba, Qb, Kb, Vt, nullptr, 1024);

  attn_kernel<<<dim3(512), dim3(256), 0, stream>>>(Qb, Kb, Vt, ctx);

  gemm_bt<1><<<dim3(8, 32), dim3(256), 0, stream>>>(
      ctx, Wt + (size_t)3072 * 1024, ba + 3072, nullptr, nullptr, nullptr, out, 1024);
}

// Round 5
// 134.527 us; speedup vs baseline: 1.0837x; 1.0837x over previous
//
#include <hip/hip_runtime.h>
#include <hip/hip_bf16.h>
#include <stdint.h>
#include <stddef.h>

using bf16 = __hip_bfloat16;
using bf16x8 = __attribute__((ext_vector_type(8))) short;   // 8 bf16 in 4 VGPRs
using f32x4  = __attribute__((ext_vector_type(4))) float;
using f32x16 = __attribute__((ext_vector_type(16))) float;
typedef unsigned int u32x2 __attribute__((ext_vector_type(2)));
typedef unsigned int u32x4 __attribute__((ext_vector_type(4)));

#define MFMA16(a, b, c) __builtin_amdgcn_mfma_f32_16x16x32_bf16((a), (b), (c), 0, 0, 0)
#define MFMA32(a, b, c) __builtin_amdgcn_mfma_f32_32x32x16_bf16((a), (b), (c), 0, 0, 0)

#define GLD16(g, l)                                                            \
  __builtin_amdgcn_global_load_lds(                                            \
      (const __attribute__((address_space(1))) void*)(g),                      \
      (__attribute__((address_space(3))) void*)(l), 16, 0, 0)

__device__ __forceinline__ float exp2_fast(float x) {
#if __has_builtin(__builtin_amdgcn_exp2f)
  return __builtin_amdgcn_exp2f(x);
#else
  return __expf(x * 0.69314718056f);
#endif
}

__device__ __forceinline__ float fmax3(float a, float b, float c) {
  return fmaxf(fmaxf(a, b), c);   // fuses to v_max3_f32
}

__device__ __forceinline__ unsigned int cvtpk_bf16(float lo, float hi) {
  unsigned int r;
  asm("v_cvt_pk_bf16_f32 %0, %1, %2" : "=v"(r) : "v"(lo), "v"(hi));
  return r;
}

__device__ __forceinline__ void permswap(unsigned int& a, unsigned int& b, int hi) {
#if __has_builtin(__builtin_amdgcn_permlane32_swap)
  u32x2 r = __builtin_amdgcn_permlane32_swap(a, b, false, false);
  a = r.x;
  b = r.y;
#else
  unsigned int sa = __shfl_xor((unsigned int)a, 32, 64);
  unsigned int sb = __shfl_xor((unsigned int)b, 32, 64);
  unsigned int an = hi ? sb : a;
  unsigned int bn = hi ? b : sa;
  a = an; b = bn;
#endif
}

// ---------------------------------------------------------------- conversions

__global__ void convert_x(const float* __restrict__ x, bf16* __restrict__ out) {
  const int i = blockIdx.x * 256 + threadIdx.x;
  const float4 v = ((const float4*)x)[i];
  __hip_bfloat162* o2 = (__hip_bfloat162*)(out + (size_t)i * 4);
  o2[0] = __float22bfloat162_rn(make_float2(v.x, v.y));
  o2[1] = __float22bfloat162_rn(make_float2(v.z, v.w));
}

__global__ void convert_w(const float* __restrict__ W0, const float* __restrict__ W1,
                          const float* __restrict__ W2, const float* __restrict__ W3,
                          bf16* __restrict__ Wt) {
  __shared__ float t[32][33];
  const int bx = blockIdx.x;
  const int mat = bx >> 10;
  const float* W = (mat == 0) ? W0 : (mat == 1) ? W1 : (mat == 2) ? W2 : W3;
  const int rem = bx & 1023;
  const int k0 = (rem >> 5) * 32, n0 = (rem & 31) * 32;
  const int c = threadIdx.x & 31, r0 = (threadIdx.x >> 5) * 4;
#pragma unroll
  for (int i = 0; i < 4; ++i) {
    const int r = r0 + i;
    t[r][c] = W[(size_t)(k0 + r) * 1024 + n0 + c];
  }
  __syncthreads();
  bf16* dst = Wt + (size_t)mat * 1024 * 1024;
#pragma unroll
  for (int i = 0; i < 4; ++i) {
    const int rn = r0 + i;
    dst[(size_t)(n0 + rn) * 1024 + k0 + c] = __float2bfloat16(t[c][rn]);
  }
}

__global__ void concat_bias(const float* __restrict__ bq, const float* __restrict__ bk,
                            const float* __restrict__ bv, const float* __restrict__ bo,
                            float* __restrict__ dst) {
  const int i = blockIdx.x * 256 + threadIdx.x;
  const float* src = (i < 1024) ? bq : (i < 2048) ? bk : (i < 3072) ? bv : bo;
  dst[i] = src[i & 1023];
}

// ---------------------------------------------------------------- GEMM (A[M,K] * Bt[N,K]^T + bias)

template <int MODE>
__global__ __launch_bounds__(256)
void gemm_bt(const bf16* __restrict__ A, const bf16* __restrict__ Bt,
             const float* __restrict__ bias,
             bf16* __restrict__ Qb, bf16* __restrict__ Kb, bf16* __restrict__ Vt,
             float* __restrict__ Of, int K) {
  __shared__ bf16 As[128 * 32];
  __shared__ bf16 Bs[128 * 32];
  const int tid = threadIdx.x;
  const int lane = tid & 63, w = tid >> 6;
  const int wr = w >> 1, wc = w & 1;
  const int lrow = lane & 15, lgk = lane >> 4;
  const int bm = blockIdx.y * 128, bn = blockIdx.x * 128;
  f32x4 acc[4][4] = {};
  const bf16* Ab = A + (size_t)bm * K;
  const bf16* Bb = Bt + (size_t)bn * K;
  const int e0 = tid, e1 = 256 + tid;

  for (int k0 = 0; k0 < K; k0 += 32) {
    GLD16(Ab + (size_t)(e0 >> 2) * K + k0 + (e0 & 3) * 8, As + e0 * 8);
    GLD16(Ab + (size_t)(e1 >> 2) * K + k0 + (e1 & 3) * 8, As + e1 * 8);
    GLD16(Bb + (size_t)(e0 >> 2) * K + k0 + (e0 & 3) * 8, Bs + e0 * 8);
    GLD16(Bb + (size_t)(e1 >> 2) * K + k0 + (e1 & 3) * 8, Bs + e1 * 8);
    asm volatile("s_waitcnt vmcnt(0)" ::: "memory");
    __syncthreads();
    bf16x8 af[4], bfr[4];
#pragma unroll
    for (int m = 0; m < 4; ++m)
      af[m] = *(const bf16x8*)(As + (wr * 64 + m * 16 + lrow) * 32 + lgk * 8);
#pragma unroll
    for (int n = 0; n < 4; ++n)
      bfr[n] = *(const bf16x8*)(Bs + (wc * 64 + n * 16 + lrow) * 32 + lgk * 8);
#pragma unroll
    for (int m = 0; m < 4; ++m)
#pragma unroll
      for (int n = 0; n < 4; ++n)
        acc[m][n] = MFMA16(af[m], bfr[n], acc[m][n]);
    __syncthreads();
  }

  if constexpr (MODE == 0) {
#pragma unroll
    for (int m = 0; m < 4; ++m) {
#pragma unroll
      for (int n = 0; n < 4; ++n) {
        const int col = bn + wc * 64 + n * 16 + lrow;
        const float bv_ = bias[col];
        const int row0 = bm + wr * 64 + m * 16 + lgk * 4;   // 4-aligned
        const int which = col >> 10;
        const int hd = col & 1023;
        const int h = hd >> 6, d = hd & 63;
        const int b = row0 >> 11, t0 = row0 & 2047;          // same b for j=0..3
        const int bh = b * 16 + h;
        if (which == 2) {
          // V: acc[m][n][0..3] are 4 consecutive tokens at fixed d ->
          // one packed 8B store into Vt[bh][d][t0..t0+3].
          uint2 pk;
          pk.x = cvtpk_bf16(acc[m][n][0] + bv_, acc[m][n][1] + bv_);
          pk.y = cvtpk_bf16(acc[m][n][2] + bv_, acc[m][n][3] + bv_);
          *(uint2*)(Vt + ((size_t)bh * 64 + d) * 2048 + t0) = pk;
        } else if (which == 0) {
#pragma unroll
          for (int j = 0; j < 4; ++j)
            Qb[((size_t)bh * 2048 + t0 + j) * 64 + d] =
                __float2bfloat16((acc[m][n][j] + bv_) * 0.18033688f);  // fold 1/8*log2e
        } else {
#pragma unroll
          for (int j = 0; j < 4; ++j)
            Kb[((size_t)bh * 2048 + t0 + j) * 64 + d] =
                __float2bfloat16(acc[m][n][j] + bv_);
        }
      }
    }
  } else {
#pragma unroll
    for (int m = 0; m < 4; ++m) {
#pragma unroll
      for (int n = 0; n < 4; ++n) {
        const int col = bn + wc * 64 + n * 16 + lrow;
        const float bv_ = bias[col];
        const int row0 = bm + wr * 64 + m * 16 + lgk * 4;
#pragma unroll
        for (int j = 0; j < 4; ++j)
          Of[(size_t)(row0 + j) * 1024 + col] = acc[m][n][j] + bv_;
      }
    }
  }
}

// ---------------------------------------------------------------- flash attention
// Swapped QK^T, in-register softmax, LDS-staged K/V (double-buffered, counted
// vmcnt, XOR-swizzle), software-pipelined: SM(t-1)/PV(t-1) overlap QK^T(t).
__global__ __launch_bounds__(256, 2)
void attn_kernel(const bf16* __restrict__ Q, const bf16* __restrict__ Kb,
                 const bf16* __restrict__ Vt, bf16* __restrict__ ctx) {
  __shared__ bf16 Kl[2][64 * 64];
  __shared__ bf16 Vl[2][64 * 64];

  const int tid = threadIdx.x, lane = tid & 63, w = tid >> 6;
  const int lo5 = lane & 31, hi = lane >> 5;

  const int bid = blockIdx.x;
  const int xcd = bid & 7, idx = bid >> 3;
  const int bh = (xcd << 2) | (idx >> 4);
  const int qt = idx & 15;
  const int q0 = qt * 128 + w * 32;

  const bf16* Qbh = Q + (size_t)bh * 2048 * 64;
  const bf16* Kbh = Kb + (size_t)bh * 2048 * 64;
  const bf16* Vbh = Vt + (size_t)bh * 64 * 2048;

  bf16x8 qf[4];
#pragma unroll
  for (int f = 0; f < 4; ++f)
    qf[f] = *(const bf16x8*)(Qbh + (size_t)(q0 + lo5) * 64 + f * 16 + hi * 8);

  f32x16 o0 = {}, o1 = {};
  float m2 = -1e30f;
  float lsum = 0.f;

  auto stage = [&](int buf, int kv) {
#pragma unroll
    for (int i = 0; i < 2; ++i) {
      const int c = (w * 2 + i) * 64 + lane;
      const int r = c >> 3, j = c & 7;
      const int js = (j ^ (r & 7)) * 8;
      GLD16(Kbh + (size_t)(kv + r) * 64 + js, &Kl[buf][c * 8]);
      GLD16(Vbh + (size_t)r * 2048 + kv + js, &Vl[buf][c * 8]);
    }
  };

  bf16x8 pa[4];

  auto softmax_pa = [&](f32x16& s0, f32x16& s1) {
    float r1[11];
#pragma unroll
    for (int i = 0; i < 5; ++i)
      r1[i] = fmax3(s0[3 * i], s0[3 * i + 1], s0[3 * i + 2]);
    r1[5] = fmax3(s0[15], s1[0], s1[1]);
#pragma unroll
    for (int i = 0; i < 4; ++i)
      r1[6 + i] = fmax3(s1[2 + 3 * i], s1[3 + 3 * i], s1[4 + 3 * i]);
    r1[10] = fmaxf(s1[14], s1[15]);
    float r2[4];
#pragma unroll
    for (int i = 0; i < 3; ++i) r2[i] = fmax3(r1[3 * i], r1[3 * i + 1], r1[3 * i + 2]);
    r2[3] = fmaxf(r1[9], r1[10]);
    const float pm = fmaxf(fmax3(r2[0], r2[1], r2[2]), r2[3]);
    if (!__all(pm <= m2 + 11.5416f)) {   // defer-max (THR=8 nats, log2 domain)
      const float mx = fmaxf(pm, __shfl_xor(pm, 32, 64));
      const float mn = fmaxf(m2, mx);
      const float corr = exp2_fast(m2 - mn);
      m2 = mn;
      lsum *= corr;
#pragma unroll
      for (int j = 0; j < 16; ++j) { o0[j] *= corr; o1[j] *= corr; }
    }
#pragma unroll
    for (int j = 0; j < 16; ++j) s0[j] = exp2_fast(s0[j] - m2);
#pragma unroll
    for (int j = 0; j < 16; ++j) s1[j] = exp2_fast(s1[j] - m2);
    float a8[8];
#pragma unroll
    for (int j = 0; j < 8; ++j) a8[j] = (s0[j] + s0[j + 8]) + (s1[j] + s1[j + 8]);
    float a4[4];
#pragma unroll
    for (int j = 0; j < 4; ++j) a4[j] = a8[j] + a8[j + 4];
    lsum += (a4[0] + a4[1]) + (a4[2] + a4[3]);
#pragma unroll
    for (int ks = 0; ks < 4; ++ks) {
      const f32x16& s = (ks < 2) ? s0 : s1;
      const int b0 = (ks & 1) * 8;
      unsigned int a0 = cvtpk_bf16(s[b0 + 0], s[b0 + 1]);
      unsigned int c0 = cvtpk_bf16(s[b0 + 4], s[b0 + 5]);
      unsigned int a1 = cvtpk_bf16(s[b0 + 2], s[b0 + 3]);
      unsigned int c1 = cvtpk_bf16(s[b0 + 6], s[b0 + 7]);
      permswap(a0, c0, hi);
      permswap(a1, c1, hi);
      u32x4 tt;
      tt.x = a0; tt.y = a1; tt.z = c0; tt.w = c1;
      pa[ks] = __builtin_bit_cast(bf16x8, tt);
    }
  };

  f32x16 sA0, sA1, sB0, sB1;
  bf16x8 vfA[8], vfB[8];

  auto step = [&](int t, f32x16& sC0, f32x16& sC1, bf16x8 (&vfC)[8],
                  f32x16& sP0, f32x16& sP1, bf16x8 (&vfP)[8]) {
    const int cur = t & 1;
    const int kv = t << 6;
    if (t < 31) stage(cur ^ 1, kv + 64);
    if (t < 31)
      asm volatile("s_waitcnt vmcnt(4)" ::: "memory");
    else
      asm volatile("s_waitcnt vmcnt(0)" ::: "memory");
    __builtin_amdgcn_s_barrier();            // B1: tile t visible
    bf16x8 kf[8];
#pragma unroll
    for (int kt = 0; kt < 2; ++kt)
#pragma unroll
      for (int f = 0; f < 4; ++f) {
        const int r = kt * 32 + lo5;
        kf[kt * 4 + f] =
            *(const bf16x8*)(&Kl[cur][(r * 8 + (((f << 1) + hi) ^ (r & 7))) * 8]);
      }
#pragma unroll
    for (int dt = 0; dt < 2; ++dt)
#pragma unroll
      for (int ks = 0; ks < 4; ++ks) {
        const int r = dt * 32 + lo5;
        vfC[dt * 4 + ks] =
            *(const bf16x8*)(&Vl[cur][(r * 8 + (((ks << 1) + hi) ^ (r & 7))) * 8]);
      }
    if (t > 0) softmax_pa(sP0, sP1);         // VALU, overlaps ds_read latency
    asm volatile("s_waitcnt lgkmcnt(0)" ::: "memory");
    __builtin_amdgcn_sched_barrier(0);
    __builtin_amdgcn_s_barrier();            // B2: reads of buf[cur] done
    __builtin_amdgcn_s_setprio(1);
    sC0 = f32x16{};
    sC1 = f32x16{};
#pragma unroll
    for (int f = 0; f < 4; ++f) sC0 = MFMA32(kf[f], qf[f], sC0);
#pragma unroll
    for (int f = 0; f < 4; ++f) sC1 = MFMA32(kf[4 + f], qf[f], sC1);
    if (t > 0) {
#pragma unroll
      for (int ks = 0; ks < 4; ++ks) {
        o0 = MFMA32(vfP[ks], pa[ks], o0);
        o1 = MFMA32(vfP[4 + ks], pa[ks], o1);
      }
    }
    __builtin_amdgcn_s_setprio(0);
  };

  stage(0, 0);

  step(0, sA0, sA1, vfA, sB0, sB1, vfB);
  for (int tt = 1; tt < 31; tt += 2) {
    step(tt, sB0, sB1, vfB, sA0, sA1, vfA);
    step(tt + 1, sA0, sA1, vfA, sB0, sB1, vfB);
  }
  step(31, sB0, sB1, vfB, sA0, sA1, vfA);

  softmax_pa(sB0, sB1);
#pragma unroll
  for (int ks = 0; ks < 4; ++ks) {
    o0 = MFMA32(vfB[ks], pa[ks], o0);
    o1 = MFMA32(vfB[4 + ks], pa[ks], o1);
  }

  lsum += __shfl_xor(lsum, 32, 64);
  const float inv = 1.f / lsum;
  const int b = bh >> 4, h = bh & 15;
  bf16* crow = ctx + (size_t)(b * 2048 + q0 + lo5) * 1024 + h * 64;
#pragma unroll
  for (int g = 0; g < 4; ++g) {
    uint2 pk0, pk1;
    pk0.x = cvtpk_bf16(o0[4 * g + 0] * inv, o0[4 * g + 1] * inv);
    pk0.y = cvtpk_bf16(o0[4 * g + 2] * inv, o0[4 * g + 3] * inv);
    pk1.x = cvtpk_bf16(o1[4 * g + 0] * inv, o1[4 * g + 1] * inv);
    pk1.y = cvtpk_bf16(o1[4 * g + 2] * inv, o1[4 * g + 3] * inv);
    *(uint2*)(crow + 8 * g + 4 * hi) = pk0;
    *(uint2*)(crow + 32 + 8 * g + 4 * hi) = pk1;
  }
}

// ---------------------------------------------------------------- launch

extern "C" void kernel_launch(void* const* d_in, const int* in_sizes, int n_in,
                              void* d_out, int out_size, void* d_ws, size_t ws_size,
                              hipStream_t stream) {
  const float* x  = (const float*)d_in[0];
  const float* Wq = (const float*)d_in[1];
  const float* bq = (const float*)d_in[2];
  const float* Wk = (const float*)d_in[3];
  const float* bk = (const float*)d_in[4];
  const float* Wv = (const float*)d_in[5];
  const float* bv = (const float*)d_in[6];
  const float* Wo = (const float*)d_in[7];
  const float* bo = (const float*)d_in[8];
  float* out = (float*)d_out;

  char* ws = (char*)d_ws;
  bf16* xb  = (bf16*)(ws);
  bf16* Wt  = (bf16*)(ws + ((size_t)8 << 20));
  bf16* Qb  = (bf16*)(ws + ((size_t)16 << 20));
  bf16* Kb  = (bf16*)(ws + ((size_t)24 << 20));
  bf16* Vt  = (bf16*)(ws + ((size_t)32 << 20));
  bf16* ctx = (bf16*)(ws + ((size_t)40 << 20));
  float* ba = (float*)(ws + ((size_t)48 << 20));

  convert_x<<<dim3(4096), dim3(256), 0, stream>>>(x, xb);
  convert_w<<<dim3(4096), dim3(256), 0, stream>>>(Wq, Wk, Wv, Wo, Wt);
  concat_bias<<<dim3(16), dim3(256), 0, stream>>>(bq, bk, bv, bo, ba);

  gemm_bt<0><<<dim3(24, 32), dim3(256), 0, stream>>>(xb, Wt, ba, Qb, Kb, Vt, nullptr, 1024);

  attn_kernel<<<dim3(512), dim3(256), 0, stream>>>(Qb, Kb, Vt, ctx);

  gemm_bt<1><<<dim3(8, 32), dim3(256), 0, stream>>>(
      ctx, Wt + (size_t)3072 * 1024, ba + 3072, nullptr, nullptr, nullptr, out, 1024);
}

// Round 6
// 126.168 us; speedup vs baseline: 1.1555x; 1.0663x over previous
//
#include <hip/hip_runtime.h>
#include <hip/hip_bf16.h>
#include <stdint.h>
#include <stddef.h>

using bf16 = __hip_bfloat16;
using bf16x8 = __attribute__((ext_vector_type(8))) short;   // 8 bf16 in 4 VGPRs
using f32x4  = __attribute__((ext_vector_type(4))) float;
using f32x16 = __attribute__((ext_vector_type(16))) float;
typedef unsigned int u32x2 __attribute__((ext_vector_type(2)));
typedef unsigned int u32x4 __attribute__((ext_vector_type(4)));

#define MFMA16(a, b, c) __builtin_amdgcn_mfma_f32_16x16x32_bf16((a), (b), (c), 0, 0, 0)
#define MFMA32(a, b, c) __builtin_amdgcn_mfma_f32_32x32x16_bf16((a), (b), (c), 0, 0, 0)

#define GLD16(g, l)                                                            \
  __builtin_amdgcn_global_load_lds(                                            \
      (const __attribute__((address_space(1))) void*)(g),                      \
      (__attribute__((address_space(3))) void*)(l), 16, 0, 0)

__device__ __forceinline__ float exp2_fast(float x) {
#if __has_builtin(__builtin_amdgcn_exp2f)
  return __builtin_amdgcn_exp2f(x);
#else
  return __expf(x * 0.69314718056f);
#endif
}

__device__ __forceinline__ float fmax3(float a, float b, float c) {
  return fmaxf(fmaxf(a, b), c);   // fuses to v_max3_f32
}

__device__ __forceinline__ unsigned int cvtpk_bf16(float lo, float hi) {
  unsigned int r;
  asm("v_cvt_pk_bf16_f32 %0, %1, %2" : "=v"(r) : "v"(lo), "v"(hi));
  return r;
}

__device__ __forceinline__ void permswap(unsigned int& a, unsigned int& b, int hi) {
#if __has_builtin(__builtin_amdgcn_permlane32_swap)
  u32x2 r = __builtin_amdgcn_permlane32_swap(a, b, false, false);
  a = r.x;
  b = r.y;
#else
  unsigned int sa = __shfl_xor((unsigned int)a, 32, 64);
  unsigned int sb = __shfl_xor((unsigned int)b, 32, 64);
  unsigned int an = hi ? sb : a;
  unsigned int bn = hi ? b : sa;
  a = an; b = bn;
#endif
}

// ---------------------------------------------------------------- conversions

__global__ void convert_x(const float* __restrict__ x, bf16* __restrict__ out) {
  const int i = blockIdx.x * 256 + threadIdx.x;
  const float4 v = ((const float4*)x)[i];
  __hip_bfloat162* o2 = (__hip_bfloat162*)(out + (size_t)i * 4);
  o2[0] = __float22bfloat162_rn(make_float2(v.x, v.y));
  o2[1] = __float22bfloat162_rn(make_float2(v.z, v.w));
}

__global__ void convert_w(const float* __restrict__ W0, const float* __restrict__ W1,
                          const float* __restrict__ W2, const float* __restrict__ W3,
                          bf16* __restrict__ Wt) {
  __shared__ float t[32][33];
  const int bx = blockIdx.x;
  const int mat = bx >> 10;
  const float* W = (mat == 0) ? W0 : (mat == 1) ? W1 : (mat == 2) ? W2 : W3;
  const int rem = bx & 1023;
  const int k0 = (rem >> 5) * 32, n0 = (rem & 31) * 32;
  const int c = threadIdx.x & 31, r0 = (threadIdx.x >> 5) * 4;
#pragma unroll
  for (int i = 0; i < 4; ++i) {
    const int r = r0 + i;
    t[r][c] = W[(size_t)(k0 + r) * 1024 + n0 + c];
  }
  __syncthreads();
  bf16* dst = Wt + (size_t)mat * 1024 * 1024;
#pragma unroll
  for (int i = 0; i < 4; ++i) {
    const int rn = r0 + i;
    dst[(size_t)(n0 + rn) * 1024 + k0 + c] = __float2bfloat16(t[c][rn]);
  }
}

__global__ void concat_bias(const float* __restrict__ bq, const float* __restrict__ bk,
                            const float* __restrict__ bv, const float* __restrict__ bo,
                            float* __restrict__ dst) {
  const int i = blockIdx.x * 256 + threadIdx.x;
  const float* src = (i < 1024) ? bq : (i < 2048) ? bk : (i < 3072) ? bv : bo;
  dst[i] = src[i & 1023];
}

// ---------------------------------------------------------------- QKV GEMM
// A[4096,1024] * Wt[3072,1024]^T + bias -> scatter Q/K/Vt.
// Single barrier per K-step, 3-buffer LDS rotation, counted vmcnt.
__global__ __launch_bounds__(256)
void gemm_qkv(const bf16* __restrict__ A, const bf16* __restrict__ Bt,
              const float* __restrict__ bias,
              bf16* __restrict__ Qb, bf16* __restrict__ Kb, bf16* __restrict__ Vt,
              int K) {
  __shared__ bf16 As[3][128 * 32];
  __shared__ bf16 Bs[3][128 * 32];
  const int tid = threadIdx.x;
  const int lane = tid & 63, w = tid >> 6;
  const int wr = w >> 1, wc = w & 1;
  const int lrow = lane & 15, lgk = lane >> 4;
  const int bm = blockIdx.y * 128, bn = blockIdx.x * 128;
  f32x4 acc[4][4] = {};
  const bf16* Ab = A + (size_t)bm * K;
  const bf16* Bb = Bt + (size_t)bn * K;
  const int e0 = tid, e1 = 256 + tid;
  const int NT = K >> 5;

  auto stage = [&](int s, int k0) {
    GLD16(Ab + (size_t)(e0 >> 2) * K + k0 + (e0 & 3) * 8, &As[s][e0 * 8]);
    GLD16(Ab + (size_t)(e1 >> 2) * K + k0 + (e1 & 3) * 8, &As[s][e1 * 8]);
    GLD16(Bb + (size_t)(e0 >> 2) * K + k0 + (e0 & 3) * 8, &Bs[s][e0 * 8]);
    GLD16(Bb + (size_t)(e1 >> 2) * K + k0 + (e1 & 3) * 8, &Bs[s][e1 * 8]);
  };

  stage(0, 0);
  stage(1, 32);
  int cur = 0, nxt = 2;
  for (int t = 0; t < NT; ++t) {
    if (t < NT - 1)
      asm volatile("s_waitcnt vmcnt(4)" ::: "memory");   // stage(t) landed
    else
      asm volatile("s_waitcnt vmcnt(0)" ::: "memory");
    __builtin_amdgcn_s_barrier();
    if (t + 2 < NT) {
      stage(nxt, (t + 2) << 5);
      nxt = (nxt == 2) ? 0 : nxt + 1;
    }
    bf16x8 af[4], bfr[4];
#pragma unroll
    for (int m = 0; m < 4; ++m)
      af[m] = *(const bf16x8*)(&As[cur][(wr * 64 + m * 16 + lrow) * 32 + lgk * 8]);
#pragma unroll
    for (int n = 0; n < 4; ++n)
      bfr[n] = *(const bf16x8*)(&Bs[cur][(wc * 64 + n * 16 + lrow) * 32 + lgk * 8]);
#pragma unroll
    for (int m = 0; m < 4; ++m)
#pragma unroll
      for (int n = 0; n < 4; ++n)
        acc[m][n] = MFMA16(af[m], bfr[n], acc[m][n]);
    cur = (cur == 2) ? 0 : cur + 1;
  }

#pragma unroll
  for (int m = 0; m < 4; ++m) {
#pragma unroll
    for (int n = 0; n < 4; ++n) {
      const int col = bn + wc * 64 + n * 16 + lrow;
      const float bv_ = bias[col];
      const int row0 = bm + wr * 64 + m * 16 + lgk * 4;   // 4-aligned
      const int which = col >> 10;
      const int hd = col & 1023;
      const int h = hd >> 6, d = hd & 63;
      const int b = row0 >> 11, t0 = row0 & 2047;
      const int bh = b * 16 + h;
      if (which == 2) {
        uint2 pk;
        pk.x = cvtpk_bf16(acc[m][n][0] + bv_, acc[m][n][1] + bv_);
        pk.y = cvtpk_bf16(acc[m][n][2] + bv_, acc[m][n][3] + bv_);
        *(uint2*)(Vt + ((size_t)bh * 64 + d) * 2048 + t0) = pk;
      } else if (which == 0) {
#pragma unroll
        for (int j = 0; j < 4; ++j)
          Qb[((size_t)bh * 2048 + t0 + j) * 64 + d] =
              __float2bfloat16((acc[m][n][j] + bv_) * 0.18033688f);  // fold 1/8*log2e
      } else {
#pragma unroll
        for (int j = 0; j < 4; ++j)
          Kb[((size_t)bh * 2048 + t0 + j) * 64 + d] =
              __float2bfloat16(acc[m][n][j] + bv_);
      }
    }
  }
}

// ---------------------------------------------------------------- O-proj GEMM
// ctx[4096,1024] * Wo^T[1024,1024] + bias -> fp32 out. 128x64 tile, 512 blocks.
__global__ __launch_bounds__(256)
void gemm_o(const bf16* __restrict__ A, const bf16* __restrict__ Bt,
            const float* __restrict__ bias, float* __restrict__ Of, int K) {
  __shared__ bf16 As[3][128 * 32];
  __shared__ bf16 Bs[3][64 * 32];
  const int tid = threadIdx.x;
  const int lane = tid & 63, w = tid >> 6;
  const int wr = w >> 1, wc = w & 1;
  const int lrow = lane & 15, lgk = lane >> 4;
  const int bm = blockIdx.y * 128, bn = blockIdx.x * 64;
  f32x4 acc[4][2] = {};
  const bf16* Ab = A + (size_t)bm * K;
  const bf16* Bb = Bt + (size_t)bn * K;
  const int e0 = tid, e1 = 256 + tid;
  const int NT = K >> 5;

  auto stage = [&](int s, int k0) {
    GLD16(Ab + (size_t)(e0 >> 2) * K + k0 + (e0 & 3) * 8, &As[s][e0 * 8]);
    GLD16(Ab + (size_t)(e1 >> 2) * K + k0 + (e1 & 3) * 8, &As[s][e1 * 8]);
    GLD16(Bb + (size_t)(e0 >> 2) * K + k0 + (e0 & 3) * 8, &Bs[s][e0 * 8]);
  };

  stage(0, 0);
  stage(1, 32);
  int cur = 0, nxt = 2;
  for (int t = 0; t < NT; ++t) {
    if (t < NT - 1)
      asm volatile("s_waitcnt vmcnt(3)" ::: "memory");
    else
      asm volatile("s_waitcnt vmcnt(0)" ::: "memory");
    __builtin_amdgcn_s_barrier();
    if (t + 2 < NT) {
      stage(nxt, (t + 2) << 5);
      nxt = (nxt == 2) ? 0 : nxt + 1;
    }
    bf16x8 af[4], bfr[2];
#pragma unroll
    for (int m = 0; m < 4; ++m)
      af[m] = *(const bf16x8*)(&As[cur][(wr * 64 + m * 16 + lrow) * 32 + lgk * 8]);
#pragma unroll
    for (int n = 0; n < 2; ++n)
      bfr[n] = *(const bf16x8*)(&Bs[cur][(wc * 32 + n * 16 + lrow) * 32 + lgk * 8]);
#pragma unroll
    for (int m = 0; m < 4; ++m)
#pragma unroll
      for (int n = 0; n < 2; ++n)
        acc[m][n] = MFMA16(af[m], bfr[n], acc[m][n]);
    cur = (cur == 2) ? 0 : cur + 1;
  }

#pragma unroll
  for (int m = 0; m < 4; ++m) {
#pragma unroll
    for (int n = 0; n < 2; ++n) {
      const int col = bn + wc * 32 + n * 16 + lrow;
      const float bv_ = bias[col];
      const int row0 = bm + wr * 64 + m * 16 + lgk * 4;
#pragma unroll
      for (int j = 0; j < 4; ++j)
        Of[(size_t)(row0 + j) * 1024 + col] = acc[m][n][j] + bv_;
    }
  }
}

// ---------------------------------------------------------------- flash attention
// Swapped QK^T, in-register softmax, LDS-staged K/V.
// 3-buffer rotation, ONE barrier per tile, counted vmcnt; SM(t-1)/PV(t-1)
// overlap QK^T(t).
__global__ __launch_bounds__(256, 2)
void attn_kernel(const bf16* __restrict__ Q, const bf16* __restrict__ Kb,
                 const bf16* __restrict__ Vt, bf16* __restrict__ ctx) {
  __shared__ bf16 Kl[3][64 * 64];
  __shared__ bf16 Vl[3][64 * 64];

  const int tid = threadIdx.x, lane = tid & 63, w = tid >> 6;
  const int lo5 = lane & 31, hi = lane >> 5;

  const int bid = blockIdx.x;
  const int xcd = bid & 7, idx = bid >> 3;
  const int bh = (xcd << 2) | (idx >> 4);
  const int qt = idx & 15;
  const int q0 = qt * 128 + w * 32;

  const bf16* Qbh = Q + (size_t)bh * 2048 * 64;
  const bf16* Kbh = Kb + (size_t)bh * 2048 * 64;
  const bf16* Vbh = Vt + (size_t)bh * 64 * 2048;

  bf16x8 qf[4];
#pragma unroll
  for (int f = 0; f < 4; ++f)
    qf[f] = *(const bf16x8*)(Qbh + (size_t)(q0 + lo5) * 64 + f * 16 + hi * 8);

  f32x16 o0 = {}, o1 = {};
  float m2 = -1e30f;
  float lsum = 0.f;

  auto stage = [&](int buf, int kv) {
#pragma unroll
    for (int i = 0; i < 2; ++i) {
      const int c = (w * 2 + i) * 64 + lane;
      const int r = c >> 3, j = c & 7;
      const int js = (j ^ (r & 7)) * 8;
      GLD16(Kbh + (size_t)(kv + r) * 64 + js, &Kl[buf][c * 8]);
      GLD16(Vbh + (size_t)r * 2048 + kv + js, &Vl[buf][c * 8]);
    }
  };

  bf16x8 pa[4];

  auto softmax_pa = [&](f32x16& s0, f32x16& s1) {
    float r1[11];
#pragma unroll
    for (int i = 0; i < 5; ++i)
      r1[i] = fmax3(s0[3 * i], s0[3 * i + 1], s0[3 * i + 2]);
    r1[5] = fmax3(s0[15], s1[0], s1[1]);
#pragma unroll
    for (int i = 0; i < 4; ++i)
      r1[6 + i] = fmax3(s1[2 + 3 * i], s1[3 + 3 * i], s1[4 + 3 * i]);
    r1[10] = fmaxf(s1[14], s1[15]);
    float r2[4];
#pragma unroll
    for (int i = 0; i < 3; ++i) r2[i] = fmax3(r1[3 * i], r1[3 * i + 1], r1[3 * i + 2]);
    r2[3] = fmaxf(r1[9], r1[10]);
    const float pm = fmaxf(fmax3(r2[0], r2[1], r2[2]), r2[3]);
    if (!__all(pm <= m2 + 11.5416f)) {   // defer-max (THR=8 nats, log2 domain)
      const float mx = fmaxf(pm, __shfl_xor(pm, 32, 64));
      const float mn = fmaxf(m2, mx);
      const float corr = exp2_fast(m2 - mn);
      m2 = mn;
      lsum *= corr;
#pragma unroll
      for (int j = 0; j < 16; ++j) { o0[j] *= corr; o1[j] *= corr; }
    }
#pragma unroll
    for (int j = 0; j < 16; ++j) s0[j] = exp2_fast(s0[j] - m2);
#pragma unroll
    for (int j = 0; j < 16; ++j) s1[j] = exp2_fast(s1[j] - m2);
    float a8[8];
#pragma unroll
    for (int j = 0; j < 8; ++j) a8[j] = (s0[j] + s0[j + 8]) + (s1[j] + s1[j + 8]);
    float a4[4];
#pragma unroll
    for (int j = 0; j < 4; ++j) a4[j] = a8[j] + a8[j + 4];
    lsum += (a4[0] + a4[1]) + (a4[2] + a4[3]);
#pragma unroll
    for (int ks = 0; ks < 4; ++ks) {
      const f32x16& s = (ks < 2) ? s0 : s1;
      const int b0 = (ks & 1) * 8;
      unsigned int a0 = cvtpk_bf16(s[b0 + 0], s[b0 + 1]);
      unsigned int c0 = cvtpk_bf16(s[b0 + 4], s[b0 + 5]);
      unsigned int a1 = cvtpk_bf16(s[b0 + 2], s[b0 + 3]);
      unsigned int c1 = cvtpk_bf16(s[b0 + 6], s[b0 + 7]);
      permswap(a0, c0, hi);
      permswap(a1, c1, hi);
      u32x4 tt;
      tt.x = a0; tt.y = a1; tt.z = c0; tt.w = c1;
      pa[ks] = __builtin_bit_cast(bf16x8, tt);
    }
  };

  f32x16 sA0, sA1, sB0, sB1;
  bf16x8 vfA[8], vfB[8];
  int cur = 0, nxt = 2;

  auto step = [&](int t, f32x16& sC0, f32x16& sC1, bf16x8 (&vfC)[8],
                  f32x16& sP0, f32x16& sP1, bf16x8 (&vfP)[8]) {
    const int kv = t << 6;
    if (t < 31)
      asm volatile("s_waitcnt vmcnt(4)" ::: "memory");   // stage(t) landed
    else
      asm volatile("s_waitcnt vmcnt(0)" ::: "memory");
    __builtin_amdgcn_s_barrier();                        // single barrier/tile
    if (t + 2 < 32) {
      stage(nxt, kv + 128);
      nxt = (nxt == 2) ? 0 : nxt + 1;
    }
    bf16x8 kf[8];
#pragma unroll
    for (int kt = 0; kt < 2; ++kt)
#pragma unroll
      for (int f = 0; f < 4; ++f) {
        const int r = kt * 32 + lo5;
        kf[kt * 4 + f] =
            *(const bf16x8*)(&Kl[cur][(r * 8 + (((f << 1) + hi) ^ (r & 7))) * 8]);
      }
#pragma unroll
    for (int dt = 0; dt < 2; ++dt)
#pragma unroll
      for (int ks = 0; ks < 4; ++ks) {
        const int r = dt * 32 + lo5;
        vfC[dt * 4 + ks] =
            *(const bf16x8*)(&Vl[cur][(r * 8 + (((ks << 1) + hi) ^ (r & 7))) * 8]);
      }
    if (t > 0) softmax_pa(sP0, sP1);   // VALU, overlaps ds_read latency
    __builtin_amdgcn_s_setprio(1);
    sC0 = f32x16{};
    sC1 = f32x16{};
#pragma unroll
    for (int f = 0; f < 4; ++f) sC0 = MFMA32(kf[f], qf[f], sC0);
#pragma unroll
    for (int f = 0; f < 4; ++f) sC1 = MFMA32(kf[4 + f], qf[f], sC1);
    if (t > 0) {
#pragma unroll
      for (int ks = 0; ks < 4; ++ks) {
        o0 = MFMA32(vfP[ks], pa[ks], o0);
        o1 = MFMA32(vfP[4 + ks], pa[ks], o1);
      }
    }
    __builtin_amdgcn_s_setprio(0);
    cur = (cur == 2) ? 0 : cur + 1;
  };

  stage(0, 0);
  stage(1, 64);

  step(0, sA0, sA1, vfA, sB0, sB1, vfB);
  for (int tt = 1; tt < 31; tt += 2) {
    step(tt, sB0, sB1, vfB, sA0, sA1, vfA);
    step(tt + 1, sA0, sA1, vfA, sB0, sB1, vfB);
  }
  step(31, sB0, sB1, vfB, sA0, sA1, vfA);

  softmax_pa(sB0, sB1);
#pragma unroll
  for (int ks = 0; ks < 4; ++ks) {
    o0 = MFMA32(vfB[ks], pa[ks], o0);
    o1 = MFMA32(vfB[4 + ks], pa[ks], o1);
  }

  lsum += __shfl_xor(lsum, 32, 64);
  const float inv = 1.f / lsum;
  const int b = bh >> 4, h = bh & 15;
  bf16* crow = ctx + (size_t)(b * 2048 + q0 + lo5) * 1024 + h * 64;
#pragma unroll
  for (int g = 0; g < 4; ++g) {
    uint2 pk0, pk1;
    pk0.x = cvtpk_bf16(o0[4 * g + 0] * inv, o0[4 * g + 1] * inv);
    pk0.y = cvtpk_bf16(o0[4 * g + 2] * inv, o0[4 * g + 3] * inv);
    pk1.x = cvtpk_bf16(o1[4 * g + 0] * inv, o1[4 * g + 1] * inv);
    pk1.y = cvtpk_bf16(o1[4 * g + 2] * inv, o1[4 * g + 3] * inv);
    *(uint2*)(crow + 8 * g + 4 * hi) = pk0;
    *(uint2*)(crow + 32 + 8 * g + 4 * hi) = pk1;
  }
}

// ---------------------------------------------------------------- launch

extern "C" void kernel_launch(void* const* d_in, const int* in_sizes, int n_in,
                              void* d_out, int out_size, void* d_ws, size_t ws_size,
                              hipStream_t stream) {
  const float* x  = (const float*)d_in[0];
  const float* Wq = (const float*)d_in[1];
  const float* bq = (const float*)d_in[2];
  const float* Wk = (const float*)d_in[3];
  const float* bk = (const float*)d_in[4];
  const float* Wv = (const float*)d_in[5];
  const float* bv = (const float*)d_in[6];
  const float* Wo = (const float*)d_in[7];
  const float* bo = (const float*)d_in[8];
  float* out = (float*)d_out;

  char* ws = (char*)d_ws;
  bf16* xb  = (bf16*)(ws);
  bf16* Wt  = (bf16*)(ws + ((size_t)8 << 20));
  bf16* Qb  = (bf16*)(ws + ((size_t)16 << 20));
  bf16* Kb  = (bf16*)(ws + ((size_t)24 << 20));
  bf16* Vt  = (bf16*)(ws + ((size_t)32 << 20));
  bf16* ctx = (bf16*)(ws + ((size_t)40 << 20));
  float* ba = (float*)(ws + ((size_t)48 << 20));

  convert_x<<<dim3(4096), dim3(256), 0, stream>>>(x, xb);
  convert_w<<<dim3(4096), dim3(256), 0, stream>>>(Wq, Wk, Wv, Wo, Wt);
  concat_bias<<<dim3(16), dim3(256), 0, stream>>>(bq, bk, bv, bo, ba);

  gemm_qkv<<<dim3(24, 32), dim3(256), 0, stream>>>(xb, Wt, ba, Qb, Kb, Vt, 1024);

  attn_kernel<<<dim3(512), dim3(256), 0, stream>>>(Qb, Kb, Vt, ctx);

  gemm_o<<<dim3(16, 32), dim3(256), 0, stream>>>(
      ctx, Wt + (size_t)3072 * 1024, ba + 3072, out, 1024);
}

// Round 7
// 123.430 us; speedup vs baseline: 1.1811x; 1.0222x over previous
//
#include <hip/hip_runtime.h>
#include <hip/hip_bf16.h>
#include <stdint.h>
#include <stddef.h>

using bf16 = __hip_bfloat16;
using bf16x8 = __attribute__((ext_vector_type(8))) short;   // 8 bf16 in 4 VGPRs
using f32x4  = __attribute__((ext_vector_type(4))) float;
using f32x16 = __attribute__((ext_vector_type(16))) float;
typedef unsigned int u32x2 __attribute__((ext_vector_type(2)));
typedef unsigned int u32x4 __attribute__((ext_vector_type(4)));

#define MFMA16(a, b, c) __builtin_amdgcn_mfma_f32_16x16x32_bf16((a), (b), (c), 0, 0, 0)
#define MFMA32(a, b, c) __builtin_amdgcn_mfma_f32_32x32x16_bf16((a), (b), (c), 0, 0, 0)

#define GLD16(g, l)                                                            \
  __builtin_amdgcn_global_load_lds(                                            \
      (const __attribute__((address_space(1))) void*)(g),                      \
      (__attribute__((address_space(3))) void*)(l), 16, 0, 0)

__device__ __forceinline__ float exp2_fast(float x) {
#if __has_builtin(__builtin_amdgcn_exp2f)
  return __builtin_amdgcn_exp2f(x);
#else
  return __expf(x * 0.69314718056f);
#endif
}

__device__ __forceinline__ float fmax3(float a, float b, float c) {
  return fmaxf(fmaxf(a, b), c);   // fuses to v_max3_f32
}

__device__ __forceinline__ unsigned int cvtpk_bf16(float lo, float hi) {
  unsigned int r;
  asm("v_cvt_pk_bf16_f32 %0, %1, %2" : "=v"(r) : "v"(lo), "v"(hi));
  return r;
}

__device__ __forceinline__ void permswap(unsigned int& a, unsigned int& b, int hi) {
#if __has_builtin(__builtin_amdgcn_permlane32_swap)
  u32x2 r = __builtin_amdgcn_permlane32_swap(a, b, false, false);
  a = r.x;
  b = r.y;
#else
  unsigned int sa = __shfl_xor((unsigned int)a, 32, 64);
  unsigned int sb = __shfl_xor((unsigned int)b, 32, 64);
  unsigned int an = hi ? sb : a;
  unsigned int bn = hi ? b : sa;
  a = an; b = bn;
#endif
}

// ---------------------------------------------------------------- conversions

__global__ void convert_x(const float* __restrict__ x, bf16* __restrict__ out) {
  const int i = blockIdx.x * 256 + threadIdx.x;
  const float4 v = ((const float4*)x)[i];
  __hip_bfloat162* o2 = (__hip_bfloat162*)(out + (size_t)i * 4);
  o2[0] = __float22bfloat162_rn(make_float2(v.x, v.y));
  o2[1] = __float22bfloat162_rn(make_float2(v.z, v.w));
}

__global__ void convert_w(const float* __restrict__ W0, const float* __restrict__ W1,
                          const float* __restrict__ W2, const float* __restrict__ W3,
                          bf16* __restrict__ Wt) {
  __shared__ float t[32][33];
  const int bx = blockIdx.x;
  const int mat = bx >> 10;
  const float* W = (mat == 0) ? W0 : (mat == 1) ? W1 : (mat == 2) ? W2 : W3;
  const int rem = bx & 1023;
  const int k0 = (rem >> 5) * 32, n0 = (rem & 31) * 32;
  const int c = threadIdx.x & 31, r0 = (threadIdx.x >> 5) * 4;
#pragma unroll
  for (int i = 0; i < 4; ++i) {
    const int r = r0 + i;
    t[r][c] = W[(size_t)(k0 + r) * 1024 + n0 + c];
  }
  __syncthreads();
  bf16* dst = Wt + (size_t)mat * 1024 * 1024;
#pragma unroll
  for (int i = 0; i < 4; ++i) {
    const int rn = r0 + i;
    dst[(size_t)(n0 + rn) * 1024 + k0 + c] = __float2bfloat16(t[c][rn]);
  }
}

__global__ void concat_bias(const float* __restrict__ bq, const float* __restrict__ bk,
                            const float* __restrict__ bv, const float* __restrict__ bo,
                            float* __restrict__ dst) {
  const int i = blockIdx.x * 256 + threadIdx.x;
  const float* src = (i < 1024) ? bq : (i < 2048) ? bk : (i < 3072) ? bv : bo;
  dst[i] = src[i & 1023];
}

// ---------------------------------------------------------------- QKV GEMM (256x256x64, 8 waves, 4-phase/K-tile)
// A[4096,1024] * Wt[3072,1024]^T + bias -> scatter Q[bh,t,d], K[bh,t,d], Vt[bh,d,t].
// m201-style: dbuf halves in LDS, counted vmcnt(2) once per K-tile, per-phase
// {ds_read || stage -> barrier -> lgkm(0) -> setprio MFMA -> barrier}, XOR-swizzled
// 16B slots via pre-swizzled global source (linear LDS dest).
__global__ __launch_bounds__(512, 2)
void gemm_qkv(const bf16* __restrict__ A, const bf16* __restrict__ Bt,
              const float* __restrict__ bias,
              bf16* __restrict__ Qb, bf16* __restrict__ Kb, bf16* __restrict__ Vt) {
  __shared__ bf16 Abuf[2][2][128 * 64];   // [dbuf][half][row*8slots*8]
  __shared__ bf16 Bbuf[2][2][128 * 64];
  const int tid = threadIdx.x;
  const int lane = tid & 63, w = tid >> 6;
  const int wr = w >> 2, wc = w & 3;           // 2 x 4 wave grid
  const int lrow = lane & 15, lgk = lane >> 4;

  // XCD-rectangular decode: 192 blocks = 16m x 12n; each XCD gets 4m x 6n.
  const int bid = blockIdx.x;
  const int xcd = bid & 7, i6 = bid >> 3;      // i6 in [0,24)
  const int xr = xcd >> 1, xc = xcd & 1;
  const int bm = (xr * 4 + (i6 & 3)) * 256;
  const int bn = (xc * 6 + (i6 >> 2)) * 256;

  f32x4 acc[8][4] = {};

  auto stageA = [&](int b, int hh, int kt) {
#pragma unroll
    for (int u = 0; u < 2; ++u) {
      const int c = u * 512 + tid;
      const int r = c >> 3, j = c & 7;
      GLD16(A + (size_t)(bm + hh * 128 + r) * 1024 + kt * 64 + ((j ^ (r & 7)) * 8),
            &Abuf[b][hh][c * 8]);
    }
  };
  auto stageB = [&](int b, int hh, int kt) {
#pragma unroll
    for (int u = 0; u < 2; ++u) {
      const int c = u * 512 + tid;
      const int r = c >> 3, j = c & 7;
      GLD16(Bt + (size_t)(bn + hh * 128 + r) * 1024 + kt * 64 + ((j ^ (r & 7)) * 8),
            &Bbuf[b][hh][c * 8]);
    }
  };

  bf16x8 a_[8];              // current mg: 4 mf x 2 kk
  bf16x8 b0_[4], b1_[4];     // ng0 / ng1: 2 nf x 2 kk

  auto readA = [&](int b, int mg, bf16x8 (&dst)[8]) {
#pragma unroll
    for (int mf = 0; mf < 4; ++mf)
#pragma unroll
      for (int kk = 0; kk < 2; ++kk) {
        const int r = (mg * 4 + mf) * 16 + lrow;
        const int s = (kk * 4 + lgk) ^ (lrow & 7);
        dst[mf * 2 + kk] = *(const bf16x8*)(&Abuf[b][wr][(r * 8 + s) * 8]);
      }
  };
  auto readB = [&](int b, int ng, bf16x8 (&dst)[4]) {
#pragma unroll
    for (int nf = 0; nf < 2; ++nf)
#pragma unroll
      for (int kk = 0; kk < 2; ++kk) {
        const int r = (wc & 1) * 64 + (ng * 2 + nf) * 16 + lrow;
        const int s = (kk * 4 + lgk) ^ (lrow & 7);
        dst[nf * 2 + kk] = *(const bf16x8*)(&Bbuf[b][wc >> 1][(r * 8 + s) * 8]);
      }
  };

  // prologue: stage K-tile 0 fully (8 loads/thread outstanding)
  stageA(0, 0, 0);
  stageA(0, 1, 0);
  stageB(0, 0, 0);
  stageB(0, 1, 0);

  for (int t = 0; t < 16; ++t) {
    const int b = t & 1, nb = b ^ 1;
    // ---- P0: sync tile t, read A[mg0]+B[ng0], MFMA mg0 x ng0
    if (t < 15) {
      stageA(nb, 0, t + 1);
      asm volatile("s_waitcnt vmcnt(2)" ::: "memory");   // tile t's 8 landed
    } else {
      asm volatile("s_waitcnt vmcnt(0)" ::: "memory");
    }
    __builtin_amdgcn_s_barrier();
    readA(b, 0, a_);
    readB(b, 0, b0_);
    asm volatile("s_waitcnt lgkmcnt(0)" ::: "memory");
    __builtin_amdgcn_sched_barrier(0);
    __builtin_amdgcn_s_setprio(1);
#pragma unroll
    for (int mf = 0; mf < 4; ++mf)
#pragma unroll
      for (int nf = 0; nf < 2; ++nf)
#pragma unroll
        for (int kk = 0; kk < 2; ++kk)
          acc[mf][nf] = MFMA16(a_[mf * 2 + kk], b0_[nf * 2 + kk], acc[mf][nf]);
    __builtin_amdgcn_s_setprio(0);
    __builtin_amdgcn_s_barrier();
    // ---- P1: read B[ng1], MFMA mg0 x ng1
    readB(b, 1, b1_);
    if (t < 15) stageA(nb, 1, t + 1);
    __builtin_amdgcn_s_barrier();
    asm volatile("s_waitcnt lgkmcnt(0)" ::: "memory");
    __builtin_amdgcn_sched_barrier(0);
    __builtin_amdgcn_s_setprio(1);
#pragma unroll
    for (int mf = 0; mf < 4; ++mf)
#pragma unroll
      for (int nf = 0; nf < 2; ++nf)
#pragma unroll
        for (int kk = 0; kk < 2; ++kk)
          acc[mf][2 + nf] = MFMA16(a_[mf * 2 + kk], b1_[nf * 2 + kk], acc[mf][2 + nf]);
    __builtin_amdgcn_s_setprio(0);
    __builtin_amdgcn_s_barrier();
    // ---- P2: read A[mg1], MFMA mg1 x ng1
    readA(b, 1, a_);
    if (t < 15) stageB(nb, 0, t + 1);
    __builtin_amdgcn_s_barrier();
    asm volatile("s_waitcnt lgkmcnt(0)" ::: "memory");
    __builtin_amdgcn_sched_barrier(0);
    __builtin_amdgcn_s_setprio(1);
#pragma unroll
    for (int mf = 0; mf < 4; ++mf)
#pragma unroll
      for (int nf = 0; nf < 2; ++nf)
#pragma unroll
        for (int kk = 0; kk < 2; ++kk)
          acc[4 + mf][2 + nf] =
              MFMA16(a_[mf * 2 + kk], b1_[nf * 2 + kk], acc[4 + mf][2 + nf]);
    __builtin_amdgcn_s_setprio(0);
    __builtin_amdgcn_s_barrier();
    // ---- P3: MFMA mg1 x ng0 (regs only)
    if (t < 15) stageB(nb, 1, t + 1);
    __builtin_amdgcn_s_setprio(1);
#pragma unroll
    for (int mf = 0; mf < 4; ++mf)
#pragma unroll
      for (int nf = 0; nf < 2; ++nf)
#pragma unroll
        for (int kk = 0; kk < 2; ++kk)
          acc[4 + mf][nf] = MFMA16(a_[mf * 2 + kk], b0_[nf * 2 + kk], acc[4 + mf][nf]);
    __builtin_amdgcn_s_setprio(0);
    __builtin_amdgcn_s_barrier();
  }

  // ---- epilogue: scatter (which is uniform per block since BN=256)
  const int which = bn >> 10;
#pragma unroll
  for (int mf = 0; mf < 8; ++mf) {
#pragma unroll
    for (int nf = 0; nf < 4; ++nf) {
      const int col = bn + wc * 64 + nf * 16 + lrow;
      const float bv_ = bias[col];
      const int row0 = bm + wr * 128 + mf * 16 + lgk * 4;
      const int hd = col & 1023;
      const int h = hd >> 6, d = hd & 63;
      const int bb = row0 >> 11, t0 = row0 & 2047;
      const int bh = bb * 16 + h;
      if (which == 2) {
        uint2 pk;
        pk.x = cvtpk_bf16(acc[mf][nf][0] + bv_, acc[mf][nf][1] + bv_);
        pk.y = cvtpk_bf16(acc[mf][nf][2] + bv_, acc[mf][nf][3] + bv_);
        *(uint2*)(Vt + ((size_t)bh * 64 + d) * 2048 + t0) = pk;
      } else if (which == 0) {
#pragma unroll
        for (int j = 0; j < 4; ++j)
          Qb[((size_t)bh * 2048 + t0 + j) * 64 + d] =
              __float2bfloat16((acc[mf][nf][j] + bv_) * 0.18033688f);  // 1/8*log2e
      } else {
#pragma unroll
        for (int j = 0; j < 4; ++j)
          Kb[((size_t)bh * 2048 + t0 + j) * 64 + d] =
              __float2bfloat16(acc[mf][nf][j] + bv_);
      }
    }
  }
}

// ---------------------------------------------------------------- O-proj GEMM
// ctx[4096,1024] * Wo^T[1024,1024] + bias -> fp32 out. 128x64 tile, 512 blocks.
__global__ __launch_bounds__(256)
void gemm_o(const bf16* __restrict__ A, const bf16* __restrict__ Bt,
            const float* __restrict__ bias, float* __restrict__ Of, int K) {
  __shared__ bf16 As[3][128 * 32];
  __shared__ bf16 Bs[3][64 * 32];
  const int tid = threadIdx.x;
  const int lane = tid & 63, w = tid >> 6;
  const int wr = w >> 1, wc = w & 1;
  const int lrow = lane & 15, lgk = lane >> 4;
  const int bm = blockIdx.y * 128, bn = blockIdx.x * 64;
  f32x4 acc[4][2] = {};
  const bf16* Ab = A + (size_t)bm * K;
  const bf16* Bb = Bt + (size_t)bn * K;
  const int e0 = tid, e1 = 256 + tid;
  const int NT = K >> 5;

  auto stage = [&](int s, int k0) {
    GLD16(Ab + (size_t)(e0 >> 2) * K + k0 + (e0 & 3) * 8, &As[s][e0 * 8]);
    GLD16(Ab + (size_t)(e1 >> 2) * K + k0 + (e1 & 3) * 8, &As[s][e1 * 8]);
    GLD16(Bb + (size_t)(e0 >> 2) * K + k0 + (e0 & 3) * 8, &Bs[s][e0 * 8]);
  };

  stage(0, 0);
  stage(1, 32);
  int cur = 0, nxt = 2;
  for (int t = 0; t < NT; ++t) {
    if (t < NT - 1)
      asm volatile("s_waitcnt vmcnt(3)" ::: "memory");
    else
      asm volatile("s_waitcnt vmcnt(0)" ::: "memory");
    __builtin_amdgcn_s_barrier();
    if (t + 2 < NT) {
      stage(nxt, (t + 2) << 5);
      nxt = (nxt == 2) ? 0 : nxt + 1;
    }
    bf16x8 af[4], bfr[2];
#pragma unroll
    for (int m = 0; m < 4; ++m)
      af[m] = *(const bf16x8*)(&As[cur][(wr * 64 + m * 16 + lrow) * 32 + lgk * 8]);
#pragma unroll
    for (int n = 0; n < 2; ++n)
      bfr[n] = *(const bf16x8*)(&Bs[cur][(wc * 32 + n * 16 + lrow) * 32 + lgk * 8]);
#pragma unroll
    for (int m = 0; m < 4; ++m)
#pragma unroll
      for (int n = 0; n < 2; ++n)
        acc[m][n] = MFMA16(af[m], bfr[n], acc[m][n]);
    cur = (cur == 2) ? 0 : cur + 1;
  }

#pragma unroll
  for (int m = 0; m < 4; ++m) {
#pragma unroll
    for (int n = 0; n < 2; ++n) {
      const int col = bn + wc * 32 + n * 16 + lrow;
      const float bv_ = bias[col];
      const int row0 = bm + wr * 64 + m * 16 + lgk * 4;
#pragma unroll
      for (int j = 0; j < 4; ++j)
        Of[(size_t)(row0 + j) * 1024 + col] = acc[m][n][j] + bv_;
    }
  }
}

// ---------------------------------------------------------------- flash attention
// Round-5 version (best measured): swapped QK^T, in-register softmax, LDS K/V
// double-buffer, vmcnt(4), two barriers/tile, SM(t-1)/PV(t-1) overlap QK^T(t).
__global__ __launch_bounds__(256, 2)
void attn_kernel(const bf16* __restrict__ Q, const bf16* __restrict__ Kb,
                 const bf16* __restrict__ Vt, bf16* __restrict__ ctx) {
  __shared__ bf16 Kl[2][64 * 64];
  __shared__ bf16 Vl[2][64 * 64];

  const int tid = threadIdx.x, lane = tid & 63, w = tid >> 6;
  const int lo5 = lane & 31, hi = lane >> 5;

  const int bid = blockIdx.x;
  const int xcd = bid & 7, idx = bid >> 3;
  const int bh = (xcd << 2) | (idx >> 4);
  const int qt = idx & 15;
  const int q0 = qt * 128 + w * 32;

  const bf16* Qbh = Q + (size_t)bh * 2048 * 64;
  const bf16* Kbh = Kb + (size_t)bh * 2048 * 64;
  const bf16* Vbh = Vt + (size_t)bh * 64 * 2048;

  bf16x8 qf[4];
#pragma unroll
  for (int f = 0; f < 4; ++f)
    qf[f] = *(const bf16x8*)(Qbh + (size_t)(q0 + lo5) * 64 + f * 16 + hi * 8);

  f32x16 o0 = {}, o1 = {};
  float m2 = -1e30f;
  float lsum = 0.f;

  auto stage = [&](int buf, int kv) {
#pragma unroll
    for (int i = 0; i < 2; ++i) {
      const int c = (w * 2 + i) * 64 + lane;
      const int r = c >> 3, j = c & 7;
      const int js = (j ^ (r & 7)) * 8;
      GLD16(Kbh + (size_t)(kv + r) * 64 + js, &Kl[buf][c * 8]);
      GLD16(Vbh + (size_t)r * 2048 + kv + js, &Vl[buf][c * 8]);
    }
  };

  bf16x8 pa[4];

  auto softmax_pa = [&](f32x16& s0, f32x16& s1) {
    float r1[11];
#pragma unroll
    for (int i = 0; i < 5; ++i)
      r1[i] = fmax3(s0[3 * i], s0[3 * i + 1], s0[3 * i + 2]);
    r1[5] = fmax3(s0[15], s1[0], s1[1]);
#pragma unroll
    for (int i = 0; i < 4; ++i)
      r1[6 + i] = fmax3(s1[2 + 3 * i], s1[3 + 3 * i], s1[4 + 3 * i]);
    r1[10] = fmaxf(s1[14], s1[15]);
    float r2[4];
#pragma unroll
    for (int i = 0; i < 3; ++i) r2[i] = fmax3(r1[3 * i], r1[3 * i + 1], r1[3 * i + 2]);
    r2[3] = fmaxf(r1[9], r1[10]);
    const float pm = fmaxf(fmax3(r2[0], r2[1], r2[2]), r2[3]);
    if (!__all(pm <= m2 + 11.5416f)) {   // defer-max (THR=8 nats, log2 domain)
      const float mx = fmaxf(pm, __shfl_xor(pm, 32, 64));
      const float mn = fmaxf(m2, mx);
      const float corr = exp2_fast(m2 - mn);
      m2 = mn;
      lsum *= corr;
#pragma unroll
      for (int j = 0; j < 16; ++j) { o0[j] *= corr; o1[j] *= corr; }
    }
#pragma unroll
    for (int j = 0; j < 16; ++j) s0[j] = exp2_fast(s0[j] - m2);
#pragma unroll
    for (int j = 0; j < 16; ++j) s1[j] = exp2_fast(s1[j] - m2);
    float a8[8];
#pragma unroll
    for (int j = 0; j < 8; ++j) a8[j] = (s0[j] + s0[j + 8]) + (s1[j] + s1[j + 8]);
    float a4[4];
#pragma unroll
    for (int j = 0; j < 4; ++j) a4[j] = a8[j] + a8[j + 4];
    lsum += (a4[0] + a4[1]) + (a4[2] + a4[3]);
#pragma unroll
    for (int ks = 0; ks < 4; ++ks) {
      const f32x16& s = (ks < 2) ? s0 : s1;
      const int b0 = (ks & 1) * 8;
      unsigned int a0 = cvtpk_bf16(s[b0 + 0], s[b0 + 1]);
      unsigned int c0 = cvtpk_bf16(s[b0 + 4], s[b0 + 5]);
      unsigned int a1 = cvtpk_bf16(s[b0 + 2], s[b0 + 3]);
      unsigned int c1 = cvtpk_bf16(s[b0 + 6], s[b0 + 7]);
      permswap(a0, c0, hi);
      permswap(a1, c1, hi);
      u32x4 tt;
      tt.x = a0; tt.y = a1; tt.z = c0; tt.w = c1;
      pa[ks] = __builtin_bit_cast(bf16x8, tt);
    }
  };

  f32x16 sA0, sA1, sB0, sB1;
  bf16x8 vfA[8], vfB[8];

  auto step = [&](int t, f32x16& sC0, f32x16& sC1, bf16x8 (&vfC)[8],
                  f32x16& sP0, f32x16& sP1, bf16x8 (&vfP)[8]) {
    const int cur = t & 1;
    const int kv = t << 6;
    if (t < 31) stage(cur ^ 1, kv + 64);
    if (t < 31)
      asm volatile("s_waitcnt vmcnt(4)" ::: "memory");
    else
      asm volatile("s_waitcnt vmcnt(0)" ::: "memory");
    __builtin_amdgcn_s_barrier();            // B1: tile t visible
    bf16x8 kf[8];
#pragma unroll
    for (int kt = 0; kt < 2; ++kt)
#pragma unroll
      for (int f = 0; f < 4; ++f) {
        const int r = kt * 32 + lo5;
        kf[kt * 4 + f] =
            *(const bf16x8*)(&Kl[cur][(r * 8 + (((f << 1) + hi) ^ (r & 7))) * 8]);
      }
#pragma unroll
    for (int dt = 0; dt < 2; ++dt)
#pragma unroll
      for (int ks = 0; ks < 4; ++ks) {
        const int r = dt * 32 + lo5;
        vfC[dt * 4 + ks] =
            *(const bf16x8*)(&Vl[cur][(r * 8 + (((ks << 1) + hi) ^ (r & 7))) * 8]);
      }
    if (t > 0) softmax_pa(sP0, sP1);         // VALU, overlaps ds_read latency
    asm volatile("s_waitcnt lgkmcnt(0)" ::: "memory");
    __builtin_amdgcn_sched_barrier(0);
    __builtin_amdgcn_s_barrier();            // B2: reads of buf[cur] done
    __builtin_amdgcn_s_setprio(1);
    sC0 = f32x16{};
    sC1 = f32x16{};
#pragma unroll
    for (int f = 0; f < 4; ++f) sC0 = MFMA32(kf[f], qf[f], sC0);
#pragma unroll
    for (int f = 0; f < 4; ++f) sC1 = MFMA32(kf[4 + f], qf[f], sC1);
    if (t > 0) {
#pragma unroll
      for (int ks = 0; ks < 4; ++ks) {
        o0 = MFMA32(vfP[ks], pa[ks], o0);
        o1 = MFMA32(vfP[4 + ks], pa[ks], o1);
      }
    }
    __builtin_amdgcn_s_setprio(0);
  };

  stage(0, 0);

  step(0, sA0, sA1, vfA, sB0, sB1, vfB);
  for (int tt = 1; tt < 31; tt += 2) {
    step(tt, sB0, sB1, vfB, sA0, sA1, vfA);
    step(tt + 1, sA0, sA1, vfA, sB0, sB1, vfB);
  }
  step(31, sB0, sB1, vfB, sA0, sA1, vfA);

  softmax_pa(sB0, sB1);
#pragma unroll
  for (int ks = 0; ks < 4; ++ks) {
    o0 = MFMA32(vfB[ks], pa[ks], o0);
    o1 = MFMA32(vfB[4 + ks], pa[ks], o1);
  }

  lsum += __shfl_xor(lsum, 32, 64);
  const float inv = 1.f / lsum;
  const int b = bh >> 4, h = bh & 15;
  bf16* crow = ctx + (size_t)(b * 2048 + q0 + lo5) * 1024 + h * 64;
#pragma unroll
  for (int g = 0; g < 4; ++g) {
    uint2 pk0, pk1;
    pk0.x = cvtpk_bf16(o0[4 * g + 0] * inv, o0[4 * g + 1] * inv);
    pk0.y = cvtpk_bf16(o0[4 * g + 2] * inv, o0[4 * g + 3] * inv);
    pk1.x = cvtpk_bf16(o1[4 * g + 0] * inv, o1[4 * g + 1] * inv);
    pk1.y = cvtpk_bf16(o1[4 * g + 2] * inv, o1[4 * g + 3] * inv);
    *(uint2*)(crow + 8 * g + 4 * hi) = pk0;
    *(uint2*)(crow + 32 + 8 * g + 4 * hi) = pk1;
  }
}

// ---------------------------------------------------------------- launch

extern "C" void kernel_launch(void* const* d_in, const int* in_sizes, int n_in,
                              void* d_out, int out_size, void* d_ws, size_t ws_size,
                              hipStream_t stream) {
  const float* x  = (const float*)d_in[0];
  const float* Wq = (const float*)d_in[1];
  const float* bq = (const float*)d_in[2];
  const float* Wk = (const float*)d_in[3];
  const float* bk = (const float*)d_in[4];
  const float* Wv = (const float*)d_in[5];
  const float* bv = (const float*)d_in[6];
  const float* Wo = (const float*)d_in[7];
  const float* bo = (const float*)d_in[8];
  float* out = (float*)d_out;

  char* ws = (char*)d_ws;
  bf16* xb  = (bf16*)(ws);
  bf16* Wt  = (bf16*)(ws + ((size_t)8 << 20));
  bf16* Qb  = (bf16*)(ws + ((size_t)16 << 20));
  bf16* Kb  = (bf16*)(ws + ((size_t)24 << 20));
  bf16* Vt  = (bf16*)(ws + ((size_t)32 << 20));
  bf16* ctx = (bf16*)(ws + ((size_t)40 << 20));
  float* ba = (float*)(ws + ((size_t)48 << 20));

  convert_x<<<dim3(4096), dim3(256), 0, stream>>>(x, xb);
  convert_w<<<dim3(4096), dim3(256), 0, stream>>>(Wq, Wk, Wv, Wo, Wt);
  concat_bias<<<dim3(16), dim3(256), 0, stream>>>(bq, bk, bv, bo, ba);

  gemm_qkv<<<dim3(192), dim3(512), 0, stream>>>(xb, Wt, ba, Qb, Kb, Vt);

  attn_kernel<<<dim3(512), dim3(256), 0, stream>>>(Qb, Kb, Vt, ctx);

  gemm_o<<<dim3(16, 32), dim3(256), 0, stream>>>(
      ctx, Wt + (size_t)3072 * 1024, ba + 3072, out, 1024);
}

// Round 8
// 122.118 us; speedup vs baseline: 1.1938x; 1.0107x over previous
//
#include <hip/hip_runtime.h>
#include <hip/hip_bf16.h>
#include <stdint.h>
#include <stddef.h>

using bf16 = __hip_bfloat16;
using bf16x8 = __attribute__((ext_vector_type(8))) short;   // 8 bf16 in 4 VGPRs
using f32x4  = __attribute__((ext_vector_type(4))) float;
using f32x16 = __attribute__((ext_vector_type(16))) float;
typedef unsigned int u32x2 __attribute__((ext_vector_type(2)));
typedef unsigned int u32x4 __attribute__((ext_vector_type(4)));

#define MFMA16(a, b, c) __builtin_amdgcn_mfma_f32_16x16x32_bf16((a), (b), (c), 0, 0, 0)
#define MFMA32(a, b, c) __builtin_amdgcn_mfma_f32_32x32x16_bf16((a), (b), (c), 0, 0, 0)

#define GLD16(g, l)                                                            \
  __builtin_amdgcn_global_load_lds(                                            \
      (const __attribute__((address_space(1))) void*)(g),                      \
      (__attribute__((address_space(3))) void*)(l), 16, 0, 0)

__device__ __forceinline__ float exp2_fast(float x) {
#if __has_builtin(__builtin_amdgcn_exp2f)
  return __builtin_amdgcn_exp2f(x);
#else
  return __expf(x * 0.69314718056f);
#endif
}

__device__ __forceinline__ float fmax3(float a, float b, float c) {
  return fmaxf(fmaxf(a, b), c);   // fuses to v_max3_f32
}

__device__ __forceinline__ unsigned int cvtpk_bf16(float lo, float hi) {
  unsigned int r;
  asm("v_cvt_pk_bf16_f32 %0, %1, %2" : "=v"(r) : "v"(lo), "v"(hi));
  return r;
}

__device__ __forceinline__ void permswap(unsigned int& a, unsigned int& b, int hi) {
#if __has_builtin(__builtin_amdgcn_permlane32_swap)
  u32x2 r = __builtin_amdgcn_permlane32_swap(a, b, false, false);
  a = r.x;
  b = r.y;
#else
  unsigned int sa = __shfl_xor((unsigned int)a, 32, 64);
  unsigned int sb = __shfl_xor((unsigned int)b, 32, 64);
  unsigned int an = hi ? sb : a;
  unsigned int bn = hi ? b : sa;
  a = an; b = bn;
#endif
}

// ---------------------------------------------------------------- conversions

__global__ void convert_x(const float* __restrict__ x, bf16* __restrict__ out) {
  const int i = blockIdx.x * 256 + threadIdx.x;
  const float4 v = ((const float4*)x)[i];
  __hip_bfloat162* o2 = (__hip_bfloat162*)(out + (size_t)i * 4);
  o2[0] = __float22bfloat162_rn(make_float2(v.x, v.y));
  o2[1] = __float22bfloat162_rn(make_float2(v.z, v.w));
}

__global__ void convert_w(const float* __restrict__ W0, const float* __restrict__ W1,
                          const float* __restrict__ W2, const float* __restrict__ W3,
                          bf16* __restrict__ Wt) {
  __shared__ float t[32][33];
  const int bx = blockIdx.x;
  const int mat = bx >> 10;
  const float* W = (mat == 0) ? W0 : (mat == 1) ? W1 : (mat == 2) ? W2 : W3;
  const int rem = bx & 1023;
  const int k0 = (rem >> 5) * 32, n0 = (rem & 31) * 32;
  const int c = threadIdx.x & 31, r0 = (threadIdx.x >> 5) * 4;
#pragma unroll
  for (int i = 0; i < 4; ++i) {
    const int r = r0 + i;
    t[r][c] = W[(size_t)(k0 + r) * 1024 + n0 + c];
  }
  __syncthreads();
  bf16* dst = Wt + (size_t)mat * 1024 * 1024;
#pragma unroll
  for (int i = 0; i < 4; ++i) {
    const int rn = r0 + i;
    dst[(size_t)(n0 + rn) * 1024 + k0 + c] = __float2bfloat16(t[c][rn]);
  }
}

__global__ void concat_bias(const float* __restrict__ bq, const float* __restrict__ bk,
                            const float* __restrict__ bv, const float* __restrict__ bo,
                            float* __restrict__ dst) {
  const int i = blockIdx.x * 256 + threadIdx.x;
  const float* src = (i < 1024) ? bq : (i < 2048) ? bk : (i < 3072) ? bv : bo;
  dst[i] = src[i & 1023];
}

// ---------------------------------------------------------------- QKV GEMM (128x384x64, 8 waves, 256 blocks = 1/CU)
// A[4096,1024] * Wt[3072,1024]^T + bias -> scatter Q[bh,t,d], K[bh,t,d], Vt[bh,d,t].
// Phase-interleaved: per K-tile 3 MFMA phases (nf-pairs), stages of t+1/t+2
// spread across phases, counted vmcnt(2) (never drained mid-loop), 2 barriers/tile.
__global__ __launch_bounds__(512, 2)
void gemm_qkv(const bf16* __restrict__ A, const bf16* __restrict__ Bt,
              const float* __restrict__ bias,
              bf16* __restrict__ Qb, bf16* __restrict__ Kb, bf16* __restrict__ Vt) {
  __shared__ bf16 Ab[2][128 * 64];   // 16 KB each
  __shared__ bf16 Bb[2][384 * 64];   // 48 KB each
  const int tid = threadIdx.x;
  const int lane = tid & 63, w = tid >> 6;
  const int wr = w >> 2, wc = w & 3;           // 2m x 4n wave grid
  const int lrow = lane & 15, lgk = lane >> 4;

  // XCD decode: 256 blocks; per XCD 8m x 4n (A ~2MB + B ~3MB L2-resident).
  const int bid = blockIdx.x;
  const int xcd = bid & 7, i5 = bid >> 3;      // i5 in [0,32)
  const int xr = xcd >> 1, xc = xcd & 1;
  const int bm = (xr * 8 + (i5 & 7)) * 128;
  const int bn = (xc * 4 + (i5 >> 3)) * 384;

  f32x4 acc[4][6] = {};

  // stage unit A: 128 rows x 8 slots = 1024 chunks, 2/thread
  auto stageA = [&](int b, int kt) {
#pragma unroll
    for (int v = 0; v < 2; ++v) {
      const int c = v * 512 + tid;
      const int r = c >> 3, j = c & 7;
      GLD16(A + (size_t)(bm + r) * 1024 + kt * 64 + ((j ^ (r & 7)) * 8),
            &Ab[b][c * 8]);
    }
  };
  // stage unit B[u]: rows u*128..u*128+127, 1024 chunks, 2/thread
  auto stageB = [&](int b, int kt, int u) {
#pragma unroll
    for (int v = 0; v < 2; ++v) {
      const int cl = v * 512 + tid;
      const int r = u * 128 + (cl >> 3), j = cl & 7;
      GLD16(Bt + (size_t)(bn + r) * 1024 + kt * 64 + ((j ^ ((r & 7))) * 8),
            &Bb[b][(r * 8 + (j)) * 8]);
    }
  };

  auto readA = [&](int b, bf16x8 (&dst)[8]) {
#pragma unroll
    for (int mf = 0; mf < 4; ++mf)
#pragma unroll
      for (int kk = 0; kk < 2; ++kk) {
        const int r = wr * 64 + mf * 16 + lrow;
        const int s = (kk * 4 + lgk) ^ (r & 7);
        dst[mf * 2 + kk] = *(const bf16x8*)(&Ab[b][(r * 8 + s) * 8]);
      }
  };
  auto readB2 = [&](int b, int nf0, bf16x8 (&dst)[4]) {
#pragma unroll
    for (int nf = 0; nf < 2; ++nf)
#pragma unroll
      for (int kk = 0; kk < 2; ++kk) {
        const int r = wc * 96 + (nf0 + nf) * 16 + lrow;
        const int s = (kk * 4 + lgk) ^ (r & 7);
        dst[nf * 2 + kk] = *(const bf16x8*)(&Bb[b][(r * 8 + s) * 8]);
      }
  };

  // prologue: tile0 fully + A(1)
  stageA(0, 0);
  stageB(0, 0, 0);
  stageB(0, 0, 1);
  stageB(0, 0, 2);
  stageA(1, 1);
  asm volatile("s_waitcnt vmcnt(2)" ::: "memory");
  __builtin_amdgcn_s_barrier();

  bf16x8 a_[8], b01[4], b23[4], b45[4];

  for (int t = 0; t < 16; ++t) {
    const int b = t & 1, nb = b ^ 1;
    // ---- PH-A: stage B0,B1(t+1); read A + B[nf0,1]; MFMA nf0,1
    if (t < 15) {
      stageB(nb, t + 1, 0);
      stageB(nb, t + 1, 1);
    }
    readA(b, a_);
    readB2(b, 0, b01);
    asm volatile("s_waitcnt lgkmcnt(0)" ::: "memory");
    __builtin_amdgcn_sched_barrier(0);
    __builtin_amdgcn_s_setprio(1);
#pragma unroll
    for (int mf = 0; mf < 4; ++mf)
#pragma unroll
      for (int nf = 0; nf < 2; ++nf)
#pragma unroll
        for (int kk = 0; kk < 2; ++kk)
          acc[mf][nf] = MFMA16(a_[mf * 2 + kk], b01[nf * 2 + kk], acc[mf][nf]);
    __builtin_amdgcn_s_setprio(0);
    // ---- PH-B: stage B2(t+1); read B[nf2,3]; MFMA nf2,3
    if (t < 15) stageB(nb, t + 1, 2);
    readB2(b, 2, b23);
    asm volatile("s_waitcnt lgkmcnt(0)" ::: "memory");
    __builtin_amdgcn_sched_barrier(0);
    __builtin_amdgcn_s_setprio(1);
#pragma unroll
    for (int mf = 0; mf < 4; ++mf)
#pragma unroll
      for (int nf = 0; nf < 2; ++nf)
#pragma unroll
        for (int kk = 0; kk < 2; ++kk)
          acc[mf][2 + nf] = MFMA16(a_[mf * 2 + kk], b23[nf * 2 + kk], acc[mf][2 + nf]);
    __builtin_amdgcn_s_setprio(0);
    // ---- PH-C: read B[nf4,5]; barrier (reads of buf b done); stage A(t+2) into b;
    //            MFMA nf4,5; counted vmcnt; barrier (tile t+1 visible)
    readB2(b, 4, b45);
    asm volatile("s_waitcnt lgkmcnt(0)" ::: "memory");
    __builtin_amdgcn_sched_barrier(0);
    __builtin_amdgcn_s_barrier();
    if (t < 14) stageA(b, t + 2);
    __builtin_amdgcn_s_setprio(1);
#pragma unroll
    for (int mf = 0; mf < 4; ++mf)
#pragma unroll
      for (int nf = 0; nf < 2; ++nf)
#pragma unroll
        for (int kk = 0; kk < 2; ++kk)
          acc[mf][4 + nf] = MFMA16(a_[mf * 2 + kk], b45[nf * 2 + kk], acc[mf][4 + nf]);
    __builtin_amdgcn_s_setprio(0);
    if (t < 14)
      asm volatile("s_waitcnt vmcnt(2)" ::: "memory");   // t+1 landed; A(t+2) in flight
    else
      asm volatile("s_waitcnt vmcnt(0)" ::: "memory");
    __builtin_amdgcn_s_barrier();
  }

  // ---- epilogue scatter
#pragma unroll
  for (int mf = 0; mf < 4; ++mf) {
#pragma unroll
    for (int nf = 0; nf < 6; ++nf) {
      const int col = bn + wc * 96 + nf * 16 + lrow;
      const float bv_ = bias[col];
      const int row0 = bm + wr * 64 + mf * 16 + lgk * 4;
      const int which = col >> 10;
      const int hd = col & 1023;
      const int h = hd >> 6, d = hd & 63;
      const int bb = row0 >> 11, t0 = row0 & 2047;
      const int bh = bb * 16 + h;
      if (which == 2) {
        uint2 pk;
        pk.x = cvtpk_bf16(acc[mf][nf][0] + bv_, acc[mf][nf][1] + bv_);
        pk.y = cvtpk_bf16(acc[mf][nf][2] + bv_, acc[mf][nf][3] + bv_);
        *(uint2*)(Vt + ((size_t)bh * 64 + d) * 2048 + t0) = pk;
      } else if (which == 0) {
#pragma unroll
        for (int j = 0; j < 4; ++j)
          Qb[((size_t)bh * 2048 + t0 + j) * 64 + d] =
              __float2bfloat16((acc[mf][nf][j] + bv_) * 0.18033688f);  // 1/8*log2e
      } else {
#pragma unroll
        for (int j = 0; j < 4; ++j)
          Kb[((size_t)bh * 2048 + t0 + j) * 64 + d] =
              __float2bfloat16(acc[mf][nf][j] + bv_);
      }
    }
  }
}

// ---------------------------------------------------------------- O-proj GEMM
// ctx[4096,1024] * Wo^T[1024,1024] + bias -> fp32 out. 128x64 tile, 512 blocks.
__global__ __launch_bounds__(256)
void gemm_o(const bf16* __restrict__ A, const bf16* __restrict__ Bt,
            const float* __restrict__ bias, float* __restrict__ Of, int K) {
  __shared__ bf16 As[3][128 * 32];
  __shared__ bf16 Bs[3][64 * 32];
  const int tid = threadIdx.x;
  const int lane = tid & 63, w = tid >> 6;
  const int wr = w >> 1, wc = w & 1;
  const int lrow = lane & 15, lgk = lane >> 4;
  const int bm = blockIdx.y * 128, bn = blockIdx.x * 64;
  f32x4 acc[4][2] = {};
  const bf16* Ab = A + (size_t)bm * K;
  const bf16* Bb = Bt + (size_t)bn * K;
  const int e0 = tid, e1 = 256 + tid;
  const int NT = K >> 5;

  auto stage = [&](int s, int k0) {
    GLD16(Ab + (size_t)(e0 >> 2) * K + k0 + (e0 & 3) * 8, &As[s][e0 * 8]);
    GLD16(Ab + (size_t)(e1 >> 2) * K + k0 + (e1 & 3) * 8, &As[s][e1 * 8]);
    GLD16(Bb + (size_t)(e0 >> 2) * K + k0 + (e0 & 3) * 8, &Bs[s][e0 * 8]);
  };

  stage(0, 0);
  stage(1, 32);
  int cur = 0, nxt = 2;
  for (int t = 0; t < NT; ++t) {
    if (t < NT - 1)
      asm volatile("s_waitcnt vmcnt(3)" ::: "memory");
    else
      asm volatile("s_waitcnt vmcnt(0)" ::: "memory");
    __builtin_amdgcn_s_barrier();
    if (t + 2 < NT) {
      stage(nxt, (t + 2) << 5);
      nxt = (nxt == 2) ? 0 : nxt + 1;
    }
    bf16x8 af[4], bfr[2];
#pragma unroll
    for (int m = 0; m < 4; ++m)
      af[m] = *(const bf16x8*)(&As[cur][(wr * 64 + m * 16 + lrow) * 32 + lgk * 8]);
#pragma unroll
    for (int n = 0; n < 2; ++n)
      bfr[n] = *(const bf16x8*)(&Bs[cur][(wc * 32 + n * 16 + lrow) * 32 + lgk * 8]);
#pragma unroll
    for (int m = 0; m < 4; ++m)
#pragma unroll
      for (int n = 0; n < 2; ++n)
        acc[m][n] = MFMA16(af[m], bfr[n], acc[m][n]);
    cur = (cur == 2) ? 0 : cur + 1;
  }

#pragma unroll
  for (int m = 0; m < 4; ++m) {
#pragma unroll
    for (int n = 0; n < 2; ++n) {
      const int col = bn + wc * 32 + n * 16 + lrow;
      const float bv_ = bias[col];
      const int row0 = bm + wr * 64 + m * 16 + lgk * 4;
#pragma unroll
      for (int j = 0; j < 4; ++j)
        Of[(size_t)(row0 + j) * 1024 + col] = acc[m][n][j] + bv_;
    }
  }
}

// ---------------------------------------------------------------- flash attention
// Best measured (round-5): swapped QK^T, in-register softmax, LDS K/V dbuf,
// vmcnt(4), two barriers/tile, SM(t-1)/PV(t-1) overlap QK^T(t).
__global__ __launch_bounds__(256, 2)
void attn_kernel(const bf16* __restrict__ Q, const bf16* __restrict__ Kb,
                 const bf16* __restrict__ Vt, bf16* __restrict__ ctx) {
  __shared__ bf16 Kl[2][64 * 64];
  __shared__ bf16 Vl[2][64 * 64];

  const int tid = threadIdx.x, lane = tid & 63, w = tid >> 6;
  const int lo5 = lane & 31, hi = lane >> 5;

  const int bid = blockIdx.x;
  const int xcd = bid & 7, idx = bid >> 3;
  const int bh = (xcd << 2) | (idx >> 4);
  const int qt = idx & 15;
  const int q0 = qt * 128 + w * 32;

  const bf16* Qbh = Q + (size_t)bh * 2048 * 64;
  const bf16* Kbh = Kb + (size_t)bh * 2048 * 64;
  const bf16* Vbh = Vt + (size_t)bh * 64 * 2048;

  bf16x8 qf[4];
#pragma unroll
  for (int f = 0; f < 4; ++f)
    qf[f] = *(const bf16x8*)(Qbh + (size_t)(q0 + lo5) * 64 + f * 16 + hi * 8);

  f32x16 o0 = {}, o1 = {};
  float m2 = -1e30f;
  float lsum = 0.f;

  auto stage = [&](int buf, int kv) {
#pragma unroll
    for (int i = 0; i < 2; ++i) {
      const int c = (w * 2 + i) * 64 + lane;
      const int r = c >> 3, j = c & 7;
      const int js = (j ^ (r & 7)) * 8;
      GLD16(Kbh + (size_t)(kv + r) * 64 + js, &Kl[buf][c * 8]);
      GLD16(Vbh + (size_t)r * 2048 + kv + js, &Vl[buf][c * 8]);
    }
  };

  bf16x8 pa[4];

  auto softmax_pa = [&](f32x16& s0, f32x16& s1) {
    float r1[11];
#pragma unroll
    for (int i = 0; i < 5; ++i)
      r1[i] = fmax3(s0[3 * i], s0[3 * i + 1], s0[3 * i + 2]);
    r1[5] = fmax3(s0[15], s1[0], s1[1]);
#pragma unroll
    for (int i = 0; i < 4; ++i)
      r1[6 + i] = fmax3(s1[2 + 3 * i], s1[3 + 3 * i], s1[4 + 3 * i]);
    r1[10] = fmaxf(s1[14], s1[15]);
    float r2[4];
#pragma unroll
    for (int i = 0; i < 3; ++i) r2[i] = fmax3(r1[3 * i], r1[3 * i + 1], r1[3 * i + 2]);
    r2[3] = fmaxf(r1[9], r1[10]);
    const float pm = fmaxf(fmax3(r2[0], r2[1], r2[2]), r2[3]);
    if (!__all(pm <= m2 + 11.5416f)) {   // defer-max (THR=8 nats, log2 domain)
      const float mx = fmaxf(pm, __shfl_xor(pm, 32, 64));
      const float mn = fmaxf(m2, mx);
      const float corr = exp2_fast(m2 - mn);
      m2 = mn;
      lsum *= corr;
#pragma unroll
      for (int j = 0; j < 16; ++j) { o0[j] *= corr; o1[j] *= corr; }
    }
#pragma unroll
    for (int j = 0; j < 16; ++j) s0[j] = exp2_fast(s0[j] - m2);
#pragma unroll
    for (int j = 0; j < 16; ++j) s1[j] = exp2_fast(s1[j] - m2);
    float a8[8];
#pragma unroll
    for (int j = 0; j < 8; ++j) a8[j] = (s0[j] + s0[j + 8]) + (s1[j] + s1[j + 8]);
    float a4[4];
#pragma unroll
    for (int j = 0; j < 4; ++j) a4[j] = a8[j] + a8[j + 4];
    lsum += (a4[0] + a4[1]) + (a4[2] + a4[3]);
#pragma unroll
    for (int ks = 0; ks < 4; ++ks) {
      const f32x16& s = (ks < 2) ? s0 : s1;
      const int b0 = (ks & 1) * 8;
      unsigned int a0 = cvtpk_bf16(s[b0 + 0], s[b0 + 1]);
      unsigned int c0 = cvtpk_bf16(s[b0 + 4], s[b0 + 5]);
      unsigned int a1 = cvtpk_bf16(s[b0 + 2], s[b0 + 3]);
      unsigned int c1 = cvtpk_bf16(s[b0 + 6], s[b0 + 7]);
      permswap(a0, c0, hi);
      permswap(a1, c1, hi);
      u32x4 tt;
      tt.x = a0; tt.y = a1; tt.z = c0; tt.w = c1;
      pa[ks] = __builtin_bit_cast(bf16x8, tt);
    }
  };

  f32x16 sA0, sA1, sB0, sB1;
  bf16x8 vfA[8], vfB[8];

  auto step = [&](int t, f32x16& sC0, f32x16& sC1, bf16x8 (&vfC)[8],
                  f32x16& sP0, f32x16& sP1, bf16x8 (&vfP)[8]) {
    const int cur = t & 1;
    const int kv = t << 6;
    if (t < 31) stage(cur ^ 1, kv + 64);
    if (t < 31)
      asm volatile("s_waitcnt vmcnt(4)" ::: "memory");
    else
      asm volatile("s_waitcnt vmcnt(0)" ::: "memory");
    __builtin_amdgcn_s_barrier();            // B1: tile t visible
    bf16x8 kf[8];
#pragma unroll
    for (int kt = 0; kt < 2; ++kt)
#pragma unroll
      for (int f = 0; f < 4; ++f) {
        const int r = kt * 32 + lo5;
        kf[kt * 4 + f] =
            *(const bf16x8*)(&Kl[cur][(r * 8 + (((f << 1) + hi) ^ (r & 7))) * 8]);
      }
#pragma unroll
    for (int dt = 0; dt < 2; ++dt)
#pragma unroll
      for (int ks = 0; ks < 4; ++ks) {
        const int r = dt * 32 + lo5;
        vfC[dt * 4 + ks] =
            *(const bf16x8*)(&Vl[cur][(r * 8 + (((ks << 1) + hi) ^ (r & 7))) * 8]);
      }
    if (t > 0) softmax_pa(sP0, sP1);         // VALU, overlaps ds_read latency
    asm volatile("s_waitcnt lgkmcnt(0)" ::: "memory");
    __builtin_amdgcn_sched_barrier(0);
    __builtin_amdgcn_s_barrier();            // B2: reads of buf[cur] done
    __builtin_amdgcn_s_setprio(1);
    sC0 = f32x16{};
    sC1 = f32x16{};
#pragma unroll
    for (int f = 0; f < 4; ++f) sC0 = MFMA32(kf[f], qf[f], sC0);
#pragma unroll
    for (int f = 0; f < 4; ++f) sC1 = MFMA32(kf[4 + f], qf[f], sC1);
    if (t > 0) {
#pragma unroll
      for (int ks = 0; ks < 4; ++ks) {
        o0 = MFMA32(vfP[ks], pa[ks], o0);
        o1 = MFMA32(vfP[4 + ks], pa[ks], o1);
      }
    }
    __builtin_amdgcn_s_setprio(0);
  };

  stage(0, 0);

  step(0, sA0, sA1, vfA, sB0, sB1, vfB);
  for (int tt = 1; tt < 31; tt += 2) {
    step(tt, sB0, sB1, vfB, sA0, sA1, vfA);
    step(tt + 1, sA0, sA1, vfA, sB0, sB1, vfB);
  }
  step(31, sB0, sB1, vfB, sA0, sA1, vfA);

  softmax_pa(sB0, sB1);
#pragma unroll
  for (int ks = 0; ks < 4; ++ks) {
    o0 = MFMA32(vfB[ks], pa[ks], o0);
    o1 = MFMA32(vfB[4 + ks], pa[ks], o1);
  }

  lsum += __shfl_xor(lsum, 32, 64);
  const float inv = 1.f / lsum;
  const int b = bh >> 4, h = bh & 15;
  bf16* crow = ctx + (size_t)(b * 2048 + q0 + lo5) * 1024 + h * 64;
#pragma unroll
  for (int g = 0; g < 4; ++g) {
    uint2 pk0, pk1;
    pk0.x = cvtpk_bf16(o0[4 * g + 0] * inv, o0[4 * g + 1] * inv);
    pk0.y = cvtpk_bf16(o0[4 * g + 2] * inv, o0[4 * g + 3] * inv);
    pk1.x = cvtpk_bf16(o1[4 * g + 0] * inv, o1[4 * g + 1] * inv);
    pk1.y = cvtpk_bf16(o1[4 * g + 2] * inv, o1[4 * g + 3] * inv);
    *(uint2*)(crow + 8 * g + 4 * hi) = pk0;
    *(uint2*)(crow + 32 + 8 * g + 4 * hi) = pk1;
  }
}

// ---------------------------------------------------------------- launch

extern "C" void kernel_launch(void* const* d_in, const int* in_sizes, int n_in,
                              void* d_out, int out_size, void* d_ws, size_t ws_size,
                              hipStream_t stream) {
  const float* x  = (const float*)d_in[0];
  const float* Wq = (const float*)d_in[1];
  const float* bq = (const float*)d_in[2];
  const float* Wk = (const float*)d_in[3];
  const float* bk = (const float*)d_in[4];
  const float* Wv = (const float*)d_in[5];
  const float* bv = (const float*)d_in[6];
  const float* Wo = (const float*)d_in[7];
  const float* bo = (const float*)d_in[8];
  float* out = (float*)d_out;

  char* ws = (char*)d_ws;
  bf16* xb  = (bf16*)(ws);
  bf16* Wt  = (bf16*)(ws + ((size_t)8 << 20));
  bf16* Qb  = (bf16*)(ws + ((size_t)16 << 20));
  bf16* Kb  = (bf16*)(ws + ((size_t)24 << 20));
  bf16* Vt  = (bf16*)(ws + ((size_t)32 << 20));
  bf16* ctx = (bf16*)(ws + ((size_t)40 << 20));
  float* ba = (float*)(ws + ((size_t)48 << 20));

  convert_x<<<dim3(4096), dim3(256), 0, stream>>>(x, xb);
  convert_w<<<dim3(4096), dim3(256), 0, stream>>>(Wq, Wk, Wv, Wo, Wt);
  concat_bias<<<dim3(16), dim3(256), 0, stream>>>(bq, bk, bv, bo, ba);

  gemm_qkv<<<dim3(256), dim3(512), 0, stream>>>(xb, Wt, ba, Qb, Kb, Vt);

  attn_kernel<<<dim3(512), dim3(256), 0, stream>>>(Qb, Kb, Vt, ctx);

  gemm_o<<<dim3(16, 32), dim3(256), 0, stream>>>(
      ctx, Wt + (size_t)3072 * 1024, ba + 3072, out, 1024);
}